// Round 12
// baseline (189.854 us; speedup 1.0000x reference)
//
#include <hip/hip_runtime.h>
#include <hip/hip_bf16.h>

// Problem dims (fixed by reference)
#define B_    8
#define C_    512
#define HW_   1024     // H*W = 32*32
#define NG    32
#define GCH   16
#define EPSV  1e-6f

typedef __attribute__((ext_vector_type(8))) short short8;   // 8 bf16 (4 VGPRs)
typedef __attribute__((ext_vector_type(4))) short short4v;  // 4 bf16
typedef __attribute__((ext_vector_type(4))) float floatx4;  // MFMA C/D

static __device__ __forceinline__ short f2bs(float f) {
  return __builtin_bit_cast(short, __float2bfloat16(f));
}
static __device__ __forceinline__ short4v pack4(float a, float b, float c, float d) {
  return (short4v){f2bs(a), f2bs(b), f2bs(c), f2bs(d)};
}
static __device__ __forceinline__ unsigned pk2(float a, float b) {
  return (unsigned)(unsigned short)f2bs(a) |
         ((unsigned)(unsigned short)f2bs(b) << 16);
}
#define MFMA(a, b, c) __builtin_amdgcn_mfma_f32_16x16x32_bf16((a), (b), (c), 0, 0, 0)

// async global->LDS, 16 B per lane (global_load_lds_dwordx4)
static __device__ __forceinline__ void glds16(const short* g, short* l) {
  __builtin_amdgcn_global_load_lds(
      (const __attribute__((address_space(1))) void*)g,
      (__attribute__((address_space(3))) void*)l, 16, 0, 0);
}

// ---------------------------------------------------------------------------
// Kernel 1 (fused): GroupNorm stats+apply+transpose AND both weight casts.
// (unchanged from r11 -- proven)
// ---------------------------------------------------------------------------
__global__ __launch_bounds__(256) void gn_cast_fused(
    const float* __restrict__ x, const float* __restrict__ gamma,
    const float* __restrict__ beta, short* __restrict__ ht,
    const float* __restrict__ w_in, short* __restrict__ wbf1,
    const float* __restrict__ w_out, short* __restrict__ wbf2) {
  int blk = blockIdx.x;
  int t = threadIdx.x;

  if (blk >= 256) {                      // ---- weight cast blocks ----
    int i = (blk - 256) * 256 + t;       // 262144 float4s total
    const float* s; short* d; int j;
    if (i < 196608) { s = w_in; d = wbf1; j = i; }
    else            { s = w_out; d = wbf2; j = i - 196608; }
    float4 v = reinterpret_cast<const float4*>(s)[j];
    reinterpret_cast<short4v*>(d)[j] = pack4(v.x, v.y, v.z, v.w);
    return;
  }

  // ---- GroupNorm block: (b, g) ----
  int b = blk >> 5, g = blk & 31;
  const float* xp = x + ((size_t)(b * C_) + g * GCH) * HW_;  // 16 ch x 1024

  __shared__ float Ls[16 * 65];          // transpose subtile (4.2 KB)
  __shared__ float rs_[4], rss_[4], st_[2];

  // phase 1: stats over 16384 elements (16 f4 per thread, coalesced)
  float s = 0.f, ss = 0.f;
  for (int i = 0; i < 16; i++) {
    float4 v = *reinterpret_cast<const float4*>(xp + (t + i * 256) * 4);
    s  += (v.x + v.y) + (v.z + v.w);
    ss += (v.x * v.x + v.y * v.y) + (v.z * v.z + v.w * v.w);
  }
  for (int o = 32; o > 0; o >>= 1) {
    s  += __shfl_down(s, o);
    ss += __shfl_down(ss, o);
  }
  int wid = t >> 6, lane = t & 63;
  if (lane == 0) { rs_[wid] = s; rss_[wid] = ss; }
  __syncthreads();
  if (t == 0) {
    float stot  = rs_[0] + rs_[1] + rs_[2] + rs_[3];
    float sstot = rss_[0] + rss_[1] + rss_[2] + rss_[3];
    float mean = stot / 16384.f;
    float var  = sstot / 16384.f - mean * mean;
    st_[0] = mean;
    st_[1] = rsqrtf(var + EPSV);
  }
  __syncthreads();

  int r = t >> 4, c4 = t & 15;
  int ch = g * GCH + r;
  float ga = gamma[ch] * st_[1];
  float be = beta[ch] - st_[0] * ga;
  int sq = t >> 2, cq = t & 3;

  // phase 2: 16 seq-subtiles of 64; x re-read (L2-hot), transpose, write
  for (int stile = 0; stile < 16; stile++) {
    int s0 = stile * 64;
    float4 v = *reinterpret_cast<const float4*>(xp + r * HW_ + s0 + c4 * 4);
    Ls[r * 65 + c4 * 4 + 0] = v.x * ga + be;
    Ls[r * 65 + c4 * 4 + 1] = v.y * ga + be;
    Ls[r * 65 + c4 * 4 + 2] = v.z * ga + be;
    Ls[r * 65 + c4 * 4 + 3] = v.w * ga + be;
    __syncthreads();
    float a0 = Ls[(cq * 4 + 0) * 65 + sq];
    float a1 = Ls[(cq * 4 + 1) * 65 + sq];
    float a2 = Ls[(cq * 4 + 2) * 65 + sq];
    float a3 = Ls[(cq * 4 + 3) * 65 + sq];
    *reinterpret_cast<short4v*>(
        ht + ((size_t)b * 1024 + s0 + sq) * 512 + g * GCH + cq * 4) =
        pack4(a0, a1, a2, a3);
    __syncthreads();
  }
}

// ---------------------------------------------------------------------------
// Kernel 2: QKV GEMM, m97 structure (unchanged from r6 -- proven).
// ---------------------------------------------------------------------------
__global__ __launch_bounds__(256) void gemm_qkv(
    const short* __restrict__ Wb, const short* __restrict__ ht,
    const float* __restrict__ bias,
    short* __restrict__ Qt, short* __restrict__ Kt, short* __restrict__ Vn) {
  __shared__ short As[2][4096];   // [buf][row*32 + k]  128 rows x 32 k
  __shared__ short Bs[2][4096];
  int bx = blockIdx.x, by = blockIdx.y, bb = blockIdx.z;
  int m0 = by * 128, n0 = bx * 128;
  int t = threadIdx.x;
  int w = t >> 6, lane = t & 63, n16 = lane & 15, quad = lane >> 4;
  int wm = (w >> 1) * 64, wn = (w & 1) * 64;

  const short* Wa = Wb + (size_t)(m0 + (t >> 2)) * 512 + (t & 3) * 8;
  const short* Xa = ht + (size_t)bb * 1024 * 512 +
                    (size_t)(n0 + (t >> 2)) * 512 + (t & 3) * 8;

#define STAGE(buf, kk)                                                \
  do {                                                                \
    glds16(Wa + (kk), &As[buf][t * 8]);                               \
    glds16(Wa + 64 * 512 + (kk), &As[buf][2048 + t * 8]);             \
    glds16(Xa + (kk), &Bs[buf][t * 8]);                               \
    glds16(Xa + 64 * 512 + (kk), &Bs[buf][2048 + t * 8]);             \
  } while (0)

  floatx4 acc[4][4];
  for (int i = 0; i < 4; i++)
    for (int j = 0; j < 4; j++) acc[i][j] = (floatx4){0.f, 0.f, 0.f, 0.f};

  STAGE(0, 0);
#pragma unroll 1
  for (int ks = 0; ks < 16; ks++) {
    int cur = ks & 1;
    __syncthreads();                       // drains staging + prior ds_reads
    if (ks < 15) STAGE(cur ^ 1, (ks + 1) * 32);
    short8 a[4], b[4];
    for (int im = 0; im < 4; im++)
      a[im] = *reinterpret_cast<const short8*>(
          &As[cur][(wm + im * 16 + n16) * 32 + quad * 8]);
    for (int in = 0; in < 4; in++)
      b[in] = *reinterpret_cast<const short8*>(
          &Bs[cur][(wn + in * 16 + n16) * 32 + quad * 8]);
    for (int im = 0; im < 4; im++)
      for (int in = 0; in < 4; in++)
        acc[im][in] = MFMA(a[im], b[in], acc[im][in]);
  }
#undef STAGE

  if (m0 < 1024) {                 // Q or K: transposed store [seq][d]
    const bool isQ = (m0 < 512);
    short* base = isQ ? Qt : Kt;
    const float sc = isQ ? 0.125f : 1.0f;   // fold 1/sqrt(64) into Q
    for (int im = 0; im < 4; im++) {
      int m = m0 + wm + im * 16 + quad * 4;
      int hh = (m >> 6) & 7, d0 = m & 63;
      float4 bi = *reinterpret_cast<const float4*>(&bias[m]);
      short* hb = base + (size_t)(bb * 8 + hh) * 1024 * 64 + d0;
      for (int in = 0; in < 4; in++) {
        int nn = n0 + wn + in * 16 + n16;
        *reinterpret_cast<short4v*>(hb + (size_t)nn * 64) =
            pack4((acc[im][in][0] + bi.x) * sc, (acc[im][in][1] + bi.y) * sc,
                  (acc[im][in][2] + bi.z) * sc, (acc[im][in][3] + bi.w) * sc);
      }
    }
  } else {                         // V: natural store [ch][seq]
    for (int im = 0; im < 4; im++) {
      int m = m0 + wm + im * 16 + quad * 4;
      float4 bi = *reinterpret_cast<const float4*>(&bias[m]);
      int ch = m - 1024;
      for (int in = 0; in < 4; in++) {
        int nn = n0 + wn + in * 16 + n16;
        short* vp = Vn + (size_t)(bb * 512 + ch) * 1024 + nn;
        vp[0]    = f2bs(acc[im][in][0] + bi.x);
        vp[1024] = f2bs(acc[im][in][1] + bi.y);
        vp[2048] = f2bs(acc[im][in][2] + bi.z);
        vp[3072] = f2bs(acc[im][in][3] + bi.w);
      }
    }
  }
}

// ---------------------------------------------------------------------------
// Kernel 3: attention v8 -- r9 no-LDS body + PINNED issue-early loads.
//   11-round synthesis: every structural fix was neutral because the
//   pressure-driven scheduler SINKS loads to just-before-use at VGPR~112-128,
//   serializing 24 x ~280cy L2 hits per kt (= the missing ~6.7k cyc/kt).
//   Fix: per iteration, issue ALL 16 loads (V-current, then K-next), then
//   __builtin_amdgcn_sched_barrier(0) -- a targeted fence the scheduler
//   cannot re-sink across -- then compute.  amdgpu_waves_per_eu(2) (min
//   only) gives a 256-VGPR budget so in-flight loads can hold registers.
//   V single-buffered: WAR on vv orders LOADV(kt+1) after PV(kt) consumed it.
// ---------------------------------------------------------------------------
__global__ __launch_bounds__(256)
__attribute__((amdgpu_waves_per_eu(2))) void attn_mfma(
    const short* __restrict__ Qt, const short* __restrict__ Kt,
    const short* __restrict__ Vn, short* __restrict__ attnT) {
  int blk0 = blockIdx.x;
  int blk = (blk0 & 7) * 64 + (blk0 >> 3);   // 512 = 8 XCD x 64: batch->XCD
  int qb = blk & 7, h = (blk >> 3) & 7, b = blk >> 6;
  int t = threadIdx.x;
  int w = t >> 6, lane = t & 63, n16 = lane & 15, quad = lane >> 4;
  int q0 = qb * 128 + w * 32;
  int qhi = quad >> 1;
  int srcA = ((quad & 1) << 5) + n16;
  int srcB = srcA + 16;

  const short* Qp = Qt + (size_t)(b * 8 + h) * 1024 * 64;
  const short* Kp = Kt + (size_t)(b * 8 + h) * 1024 * 64;
  const short* Vp = Vn + (size_t)(b * 512 + h * 64) * 1024;

  short8 qa[2][2];
  for (int qt = 0; qt < 2; qt++)
    for (int f = 0; f < 2; f++)
      qa[qt][f] = *reinterpret_cast<const short8*>(
          Qp + (size_t)(q0 + qt * 16 + n16) * 64 + f * 32 + quad * 8);

  floatx4 O[2][4];
  float l[2] = {0.f, 0.f};
  for (int qt = 0; qt < 2; qt++)
    for (int i = 0; i < 4; i++) O[qt][i] = (floatx4){0.f, 0.f, 0.f, 0.f};

#define LOADK(dst, ktv)                                                      \
  do {                                                                       \
    int k0_ = (ktv) * 64;                                                    \
    for (int nt_ = 0; nt_ < 4; nt_++)                                        \
      for (int f_ = 0; f_ < 2; f_++)                                         \
        dst[nt_][f_] = *reinterpret_cast<const short8*>(                     \
            Kp + (size_t)(k0_ + nt_ * 16 + n16) * 64 + f_ * 32 + quad * 8);  \
  } while (0)

#define LOADV(dst, ktv)                                                      \
  do {                                                                       \
    int k0_ = (ktv) * 64;                                                    \
    for (int nd_ = 0; nd_ < 4; nd_++) {                                      \
      const short* vs_ =                                                     \
          Vp + (size_t)(nd_ * 16 + n16) * 1024 + k0_ + quad * 8;             \
      dst[nd_][0] = *reinterpret_cast<const short8*>(vs_);                   \
      dst[nd_][1] = *reinterpret_cast<const short8*>(vs_ + 32);              \
    }                                                                        \
  } while (0)

// compute-only body: QK (swapped) -> in-reg softmax -> PV, using kf and vv
#define BODYC(kf, vv)                                                        \
  do {                                                                       \
    _Pragma("unroll")                                                        \
    for (int qt_ = 0; qt_ < 2; qt_++) {                                      \
      floatx4 T_[4];                                                         \
      _Pragma("unroll")                                                      \
      for (int nt_ = 0; nt_ < 4; nt_++) {                                    \
        floatx4 s_ = (floatx4){0.f, 0.f, 0.f, 0.f};                          \
        s_ = MFMA(kf[nt_][0], qa[qt_][0], s_);                               \
        T_[nt_] = MFMA(kf[nt_][1], qa[qt_][1], s_);                          \
      }                                                                      \
      unsigned u_[4][2];                                                     \
      _Pragma("unroll")                                                      \
      for (int nt_ = 0; nt_ < 4; nt_++) {                                    \
        float p0_ = __expf(T_[nt_][0]);                                      \
        float p1_ = __expf(T_[nt_][1]);                                      \
        float p2_ = __expf(T_[nt_][2]);                                      \
        float p3_ = __expf(T_[nt_][3]);                                      \
        l[qt_] += (p0_ + p1_) + (p2_ + p3_);                                 \
        u_[nt_][0] = pk2(p0_, p1_);                                          \
        u_[nt_][1] = pk2(p2_, p3_);                                          \
      }                                                                      \
      short8 pa_[2];                                                         \
      _Pragma("unroll")                                                      \
      for (int f_ = 0; f_ < 2; f_++) {                                       \
        unsigned a0_ = (unsigned)__shfl((int)u_[2 * f_ + 0][0], srcA);       \
        unsigned a1_ = (unsigned)__shfl((int)u_[2 * f_ + 1][0], srcA);       \
        unsigned b0_ = (unsigned)__shfl((int)u_[2 * f_ + 0][1], srcA);       \
        unsigned b1_ = (unsigned)__shfl((int)u_[2 * f_ + 1][1], srcA);       \
        unsigned c0_ = (unsigned)__shfl((int)u_[2 * f_ + 0][0], srcB);       \
        unsigned c1_ = (unsigned)__shfl((int)u_[2 * f_ + 1][0], srcB);       \
        unsigned d0_ = (unsigned)__shfl((int)u_[2 * f_ + 0][1], srcB);       \
        unsigned d1_ = (unsigned)__shfl((int)u_[2 * f_ + 1][1], srcB);       \
        uint4 wv_;                                                           \
        wv_.x = qhi ? a1_ : a0_;                                             \
        wv_.y = qhi ? b1_ : b0_;                                             \
        wv_.z = qhi ? c1_ : c0_;                                             \
        wv_.w = qhi ? d1_ : d0_;                                             \
        pa_[f_] = __builtin_bit_cast(short8, wv_);                           \
      }                                                                      \
      __builtin_amdgcn_s_setprio(1);                                         \
      _Pragma("unroll")                                                      \
      for (int nd_ = 0; nd_ < 4; nd_++) {                                    \
        O[qt_][nd_] = MFMA(pa_[0], vv[nd_][0], O[qt_][nd_]);                 \
        O[qt_][nd_] = MFMA(pa_[1], vv[nd_][1], O[qt_][nd_]);                 \
      }                                                                      \
      __builtin_amdgcn_s_setprio(0);                                         \
    }                                                                        \
  } while (0)

  short8 kfA[4][2], kfB[4][2], vv[4][2];
  LOADK(kfA, 0);
#pragma unroll 1
  for (int kt = 0; kt < 16; kt += 2) {
    // iteration A (kt): issue V(kt) + K(kt+1), fence, compute with kfA
    LOADV(vv, kt);
    LOADK(kfB, kt + 1);
    __builtin_amdgcn_sched_barrier(0);
    BODYC(kfA, vv);
    // iteration B (kt+1): issue V(kt+1) + K(kt+2), fence, compute with kfB
    LOADV(vv, kt + 1);
    if (kt + 2 < 16) LOADK(kfA, kt + 2);
    __builtin_amdgcn_sched_barrier(0);
    BODYC(kfB, vv);
  }
#undef LOADK
#undef LOADV
#undef BODYC

  // epilogue: l is per-q (q=n16), spread over quads -> reduce over quads,
  // then each lane fetches l for its output rows q=quad*4+r via shfl.
  for (int qt = 0; qt < 2; qt++) {
    float s = l[qt];
    s += __shfl_xor(s, 16);
    s += __shfl_xor(s, 32);
    for (int nd = 0; nd < 4; nd++)
      for (int r = 0; r < 4; r++) {
        float linv = 1.0f / __shfl(s, quad * 4 + r);
        int q = q0 + qt * 16 + quad * 4 + r;
        int ch = h * 64 + nd * 16 + n16;
        attnT[((size_t)b * 1024 + q) * 512 + ch] = f2bs(O[qt][nd][r] * linv);
      }
  }
}

// ---------------------------------------------------------------------------
// Kernel 4: projection GEMM + bias + residual, 64x64 tiles (r7, kept).
// ---------------------------------------------------------------------------
__global__ __launch_bounds__(256) void gemm_out(
    const short* __restrict__ Wb, const short* __restrict__ Xt,
    const float* __restrict__ bias, const float* __restrict__ resid,
    float* __restrict__ out) {
  __shared__ short As[2][2048];   // 64 rows x 32 k
  __shared__ short Bs[2][2048];
  int bx = blockIdx.x, by = blockIdx.y, bb = blockIdx.z;
  int m0 = by * 64, n0 = bx * 64;
  int t = threadIdx.x;
  int w = t >> 6, lane = t & 63, n16 = lane & 15, quad = lane >> 4;
  int wm = (w >> 1) * 32, wn = (w & 1) * 32;

  const short* Wa = Wb + (size_t)(m0 + (t >> 2)) * 512 + (t & 3) * 8;
  const short* Xa = Xt + (size_t)bb * 1024 * 512 +
                    (size_t)(n0 + (t >> 2)) * 512 + (t & 3) * 8;

#define STAGE(buf, kk)                                                \
  do {                                                                \
    glds16(Wa + (kk), &As[buf][t * 8]);                               \
    glds16(Xa + (kk), &Bs[buf][t * 8]);                               \
  } while (0)

  floatx4 acc[2][2];
  for (int i = 0; i < 2; i++)
    for (int j = 0; j < 2; j++) acc[i][j] = (floatx4){0.f, 0.f, 0.f, 0.f};

  STAGE(0, 0);
#pragma unroll 1
  for (int ks = 0; ks < 16; ks++) {
    int cur = ks & 1;
    __syncthreads();
    if (ks < 15) STAGE(cur ^ 1, (ks + 1) * 32);
    short8 a[2], b[2];
    for (int im = 0; im < 2; im++)
      a[im] = *reinterpret_cast<const short8*>(
          &As[cur][(wm + im * 16 + n16) * 32 + quad * 8]);
    for (int in = 0; in < 2; in++)
      b[in] = *reinterpret_cast<const short8*>(
          &Bs[cur][(wn + in * 16 + n16) * 32 + quad * 8]);
    for (int im = 0; im < 2; im++)
      for (int in = 0; in < 2; in++)
        acc[im][in] = MFMA(a[im], b[in], acc[im][in]);
  }
#undef STAGE

  for (int im = 0; im < 2; im++) {
    int m = m0 + wm + im * 16 + quad * 4;
    float4 bi = *reinterpret_cast<const float4*>(&bias[m]);
    for (int in = 0; in < 2; in++) {
      int nn = n0 + wn + in * 16 + n16;
      size_t idx = ((size_t)bb * 512 + m) * 1024 + nn;
      out[idx]        = acc[im][in][0] + bi.x + resid[idx];
      out[idx + 1024] = acc[im][in][1] + bi.y + resid[idx + 1024];
      out[idx + 2048] = acc[im][in][2] + bi.z + resid[idx + 2048];
      out[idx + 3072] = acc[im][in][3] + bi.w + resid[idx + 3072];
    }
  }
}

// ---------------------------------------------------------------------------
extern "C" void kernel_launch(void* const* d_in, const int* in_sizes, int n_in,
                              void* d_out, int out_size, void* d_ws, size_t ws_size,
                              hipStream_t stream) {
  const float* x     = (const float*)d_in[0];
  const float* gamma = (const float*)d_in[1];
  const float* beta  = (const float*)d_in[2];
  const float* w_in  = (const float*)d_in[3];
  const float* b_in  = (const float*)d_in[4];
  const float* w_out = (const float*)d_in[5];
  const float* b_out = (const float*)d_in[6];
  float* out = (float*)d_out;

  char* ws = (char*)d_ws;
  short* ht    = (short*)ws;                    //  8 MiB [8][1024][512]
  short* Qt    = (short*)(ws + (8u  << 20));    //  8 MiB [64][1024][64]
  short* Kt    = (short*)(ws + (16u << 20));    //  8 MiB [64][1024][64]
  short* Vn    = (short*)(ws + (24u << 20));    //  8 MiB [8][512][1024]
  short* attnT = (short*)(ws + (32u << 20));    //  8 MiB [8][1024][512]
  short* wbf1  = (short*)(ws + (40u << 20));    //  1.5 MiB
  short* wbf2  = (short*)(ws + (42u << 20));    //  0.5 MiB

  gn_cast_fused<<<1280, 256, 0, stream>>>(x, gamma, beta, ht,
                                          w_in, wbf1, w_out, wbf2);
  gemm_qkv<<<dim3(8, 12, B_), 256, 0, stream>>>(wbf1, ht, b_in, Qt, Kt, Vn);
  attn_mfma<<<512, 256, 0, stream>>>(Qt, Kt, Vn, attnT);
  gemm_out<<<dim3(16, 8, B_), 256, 0, stream>>>(wbf2, attnT, b_out, x, out);
}

// Round 13
// 184.599 us; speedup vs baseline: 1.0285x; 1.0285x over previous
//
#include <hip/hip_runtime.h>
#include <hip/hip_bf16.h>

// Problem dims (fixed by reference)
#define B_    8
#define C_    512
#define HW_   1024     // H*W = 32*32
#define NG    32
#define GCH   16
#define EPSV  1e-6f

typedef __attribute__((ext_vector_type(8))) short short8;   // 8 bf16 (4 VGPRs)
typedef __attribute__((ext_vector_type(4))) short short4v;  // 4 bf16
typedef __attribute__((ext_vector_type(4))) float floatx4;  // MFMA C/D

static __device__ __forceinline__ short f2bs(float f) {
  return __builtin_bit_cast(short, __float2bfloat16(f));
}
static __device__ __forceinline__ short4v pack4(float a, float b, float c, float d) {
  return (short4v){f2bs(a), f2bs(b), f2bs(c), f2bs(d)};
}
static __device__ __forceinline__ unsigned pk2(float a, float b) {
  return (unsigned)(unsigned short)f2bs(a) |
         ((unsigned)(unsigned short)f2bs(b) << 16);
}
#define MFMA(a, b, c) __builtin_amdgcn_mfma_f32_16x16x32_bf16((a), (b), (c), 0, 0, 0)

// async global->LDS, 16 B per lane (global_load_lds_dwordx4)
static __device__ __forceinline__ void glds16(const short* g, short* l) {
  __builtin_amdgcn_global_load_lds(
      (const __attribute__((address_space(1))) void*)g,
      (__attribute__((address_space(3))) void*)l, 16, 0, 0);
}

// ---------------------------------------------------------------------------
// Kernel 1 (fused): GroupNorm stats+apply+transpose AND both weight casts.
//   r13: phase-2 batches 4 subtiles per barrier pair (32 -> 8 syncthreads).
// ---------------------------------------------------------------------------
__global__ __launch_bounds__(256) void gn_cast_fused(
    const float* __restrict__ x, const float* __restrict__ gamma,
    const float* __restrict__ beta, short* __restrict__ ht,
    const float* __restrict__ w_in, short* __restrict__ wbf1,
    const float* __restrict__ w_out, short* __restrict__ wbf2) {
  int blk = blockIdx.x;
  int t = threadIdx.x;

  if (blk >= 256) {                      // ---- weight cast blocks ----
    int i = (blk - 256) * 256 + t;       // 262144 float4s total
    const float* s; short* d; int j;
    if (i < 196608) { s = w_in; d = wbf1; j = i; }
    else            { s = w_out; d = wbf2; j = i - 196608; }
    float4 v = reinterpret_cast<const float4*>(s)[j];
    reinterpret_cast<short4v*>(d)[j] = pack4(v.x, v.y, v.z, v.w);
    return;
  }

  // ---- GroupNorm block: (b, g) ----
  int b = blk >> 5, g = blk & 31;
  const float* xp = x + ((size_t)(b * C_) + g * GCH) * HW_;  // 16 ch x 1024

  __shared__ float Ls[4 * 1040];         // 4 subtiles of [16][65]  16.6 KB
  __shared__ float rs_[4], rss_[4], st_[2];

  // phase 1: stats over 16384 elements (16 f4 per thread, coalesced)
  float s = 0.f, ss = 0.f;
  for (int i = 0; i < 16; i++) {
    float4 v = *reinterpret_cast<const float4*>(xp + (t + i * 256) * 4);
    s  += (v.x + v.y) + (v.z + v.w);
    ss += (v.x * v.x + v.y * v.y) + (v.z * v.z + v.w * v.w);
  }
  for (int o = 32; o > 0; o >>= 1) {
    s  += __shfl_down(s, o);
    ss += __shfl_down(ss, o);
  }
  int wid = t >> 6, lane = t & 63;
  if (lane == 0) { rs_[wid] = s; rss_[wid] = ss; }
  __syncthreads();
  if (t == 0) {
    float stot  = rs_[0] + rs_[1] + rs_[2] + rs_[3];
    float sstot = rss_[0] + rss_[1] + rss_[2] + rss_[3];
    float mean = stot / 16384.f;
    float var  = sstot / 16384.f - mean * mean;
    st_[0] = mean;
    st_[1] = rsqrtf(var + EPSV);
  }
  __syncthreads();

  int r = t >> 4, c4 = t & 15;
  int ch = g * GCH + r;
  float ga = gamma[ch] * st_[1];
  float be = beta[ch] - st_[0] * ga;
  int sq = t >> 2, cq = t & 3;

  // phase 2: 4 outer iters x 4 subtiles; x re-read (L2-hot), transpose, write
  for (int it = 0; it < 4; it++) {
    for (int sub = 0; sub < 4; sub++) {
      int s0 = (it * 4 + sub) * 64;
      float4 v = *reinterpret_cast<const float4*>(xp + r * HW_ + s0 + c4 * 4);
      float* L = Ls + sub * 1040;
      L[r * 65 + c4 * 4 + 0] = v.x * ga + be;
      L[r * 65 + c4 * 4 + 1] = v.y * ga + be;
      L[r * 65 + c4 * 4 + 2] = v.z * ga + be;
      L[r * 65 + c4 * 4 + 3] = v.w * ga + be;
    }
    __syncthreads();
    for (int sub = 0; sub < 4; sub++) {
      int s0 = (it * 4 + sub) * 64;
      const float* L = Ls + sub * 1040;
      float a0 = L[(cq * 4 + 0) * 65 + sq];
      float a1 = L[(cq * 4 + 1) * 65 + sq];
      float a2 = L[(cq * 4 + 2) * 65 + sq];
      float a3 = L[(cq * 4 + 3) * 65 + sq];
      *reinterpret_cast<short4v*>(
          ht + ((size_t)b * 1024 + s0 + sq) * 512 + g * GCH + cq * 4) =
          pack4(a0, a1, a2, a3);
    }
    __syncthreads();
  }
}

// ---------------------------------------------------------------------------
// Kernel 2: QKV GEMM, m97 structure (unchanged from r6 -- proven).
// ---------------------------------------------------------------------------
__global__ __launch_bounds__(256) void gemm_qkv(
    const short* __restrict__ Wb, const short* __restrict__ ht,
    const float* __restrict__ bias,
    short* __restrict__ Qt, short* __restrict__ Kt, short* __restrict__ Vn) {
  __shared__ short As[2][4096];   // [buf][row*32 + k]  128 rows x 32 k
  __shared__ short Bs[2][4096];
  int bx = blockIdx.x, by = blockIdx.y, bb = blockIdx.z;
  int m0 = by * 128, n0 = bx * 128;
  int t = threadIdx.x;
  int w = t >> 6, lane = t & 63, n16 = lane & 15, quad = lane >> 4;
  int wm = (w >> 1) * 64, wn = (w & 1) * 64;

  const short* Wa = Wb + (size_t)(m0 + (t >> 2)) * 512 + (t & 3) * 8;
  const short* Xa = ht + (size_t)bb * 1024 * 512 +
                    (size_t)(n0 + (t >> 2)) * 512 + (t & 3) * 8;

#define STAGE(buf, kk)                                                \
  do {                                                                \
    glds16(Wa + (kk), &As[buf][t * 8]);                               \
    glds16(Wa + 64 * 512 + (kk), &As[buf][2048 + t * 8]);             \
    glds16(Xa + (kk), &Bs[buf][t * 8]);                               \
    glds16(Xa + 64 * 512 + (kk), &Bs[buf][2048 + t * 8]);             \
  } while (0)

  floatx4 acc[4][4];
  for (int i = 0; i < 4; i++)
    for (int j = 0; j < 4; j++) acc[i][j] = (floatx4){0.f, 0.f, 0.f, 0.f};

  STAGE(0, 0);
#pragma unroll 1
  for (int ks = 0; ks < 16; ks++) {
    int cur = ks & 1;
    __syncthreads();                       // drains staging + prior ds_reads
    if (ks < 15) STAGE(cur ^ 1, (ks + 1) * 32);
    short8 a[4], b[4];
    for (int im = 0; im < 4; im++)
      a[im] = *reinterpret_cast<const short8*>(
          &As[cur][(wm + im * 16 + n16) * 32 + quad * 8]);
    for (int in = 0; in < 4; in++)
      b[in] = *reinterpret_cast<const short8*>(
          &Bs[cur][(wn + in * 16 + n16) * 32 + quad * 8]);
    for (int im = 0; im < 4; im++)
      for (int in = 0; in < 4; in++)
        acc[im][in] = MFMA(a[im], b[in], acc[im][in]);
  }
#undef STAGE

  if (m0 < 1024) {                 // Q or K: transposed store [seq][d]
    const bool isQ = (m0 < 512);
    short* base = isQ ? Qt : Kt;
    const float sc = isQ ? 0.125f : 1.0f;   // fold 1/sqrt(64) into Q
    for (int im = 0; im < 4; im++) {
      int m = m0 + wm + im * 16 + quad * 4;
      int hh = (m >> 6) & 7, d0 = m & 63;
      float4 bi = *reinterpret_cast<const float4*>(&bias[m]);
      short* hb = base + (size_t)(bb * 8 + hh) * 1024 * 64 + d0;
      for (int in = 0; in < 4; in++) {
        int nn = n0 + wn + in * 16 + n16;
        *reinterpret_cast<short4v*>(hb + (size_t)nn * 64) =
            pack4((acc[im][in][0] + bi.x) * sc, (acc[im][in][1] + bi.y) * sc,
                  (acc[im][in][2] + bi.z) * sc, (acc[im][in][3] + bi.w) * sc);
      }
    }
  } else {                         // V: natural store [ch][seq]
    for (int im = 0; im < 4; im++) {
      int m = m0 + wm + im * 16 + quad * 4;
      float4 bi = *reinterpret_cast<const float4*>(&bias[m]);
      int ch = m - 1024;
      for (int in = 0; in < 4; in++) {
        int nn = n0 + wn + in * 16 + n16;
        short* vp = Vn + (size_t)(bb * 512 + ch) * 1024 + nn;
        vp[0]    = f2bs(acc[im][in][0] + bi.x);
        vp[1024] = f2bs(acc[im][in][1] + bi.y);
        vp[2048] = f2bs(acc[im][in][2] + bi.z);
        vp[3072] = f2bs(acc[im][in][3] + bi.w);
      }
    }
  }
}

// ---------------------------------------------------------------------------
// Kernel 3: attention v9 -- r9 no-LDS swapped-QK body, KVBLK 64 -> 128.
//   12 rounds: wall ~= kt_count x (chain depth + fixed overhead), invariant
//   to occupancy/memory/LDS/scheduling.  The one untried axis: kt_count.
//   KVBLK=128 halves traversals 16 -> 8 at identical total work; the wider
//   body adds parallel width, not serial depth.  kf[8][2] (64 VGPR) live
//   only through QK; pa[2][4]; V in two WAR-ordered halves (vv stays 32).
//   waves_per_eu(2) grants the 256-VGPR budget (peak ~190).
// ---------------------------------------------------------------------------
__global__ __launch_bounds__(256)
__attribute__((amdgpu_waves_per_eu(2))) void attn_mfma(
    const short* __restrict__ Qt, const short* __restrict__ Kt,
    const short* __restrict__ Vn, short* __restrict__ attnT) {
  int blk0 = blockIdx.x;
  int blk = (blk0 & 7) * 64 + (blk0 >> 3);   // 512 = 8 XCD x 64: batch->XCD
  int qb = blk & 7, h = (blk >> 3) & 7, b = blk >> 6;
  int t = threadIdx.x;
  int w = t >> 6, lane = t & 63, n16 = lane & 15, quad = lane >> 4;
  int q0 = qb * 128 + w * 32;
  int qhi = quad >> 1;
  int srcA = ((quad & 1) << 5) + n16;
  int srcB = srcA + 16;

  const short* Qp = Qt + (size_t)(b * 8 + h) * 1024 * 64;
  const short* Kp = Kt + (size_t)(b * 8 + h) * 1024 * 64;
  const short* Vp = Vn + (size_t)(b * 512 + h * 64) * 1024;

  short8 qa[2][2];
  for (int qt = 0; qt < 2; qt++)
    for (int f = 0; f < 2; f++)
      qa[qt][f] = *reinterpret_cast<const short8*>(
          Qp + (size_t)(q0 + qt * 16 + n16) * 64 + f * 32 + quad * 8);

  floatx4 O[2][4];
  float l[2] = {0.f, 0.f};
  for (int qt = 0; qt < 2; qt++)
    for (int i = 0; i < 4; i++) O[qt][i] = (floatx4){0.f, 0.f, 0.f, 0.f};

  short8 kf[8][2];   // 128-kv K tile (64 VGPR, dead after QK)
  short8 vv[4][2];   // one 64-kv V half at a time

#pragma unroll 1
  for (int kt = 0; kt < 8; kt++) {
    int k0 = kt * 128;
    // K tile: 16 loads to distinct regs (no WAW within iteration)
#pragma unroll
    for (int nt = 0; nt < 8; nt++)
#pragma unroll
      for (int f = 0; f < 2; f++)
        kf[nt][f] = *reinterpret_cast<const short8*>(
            Kp + (size_t)(k0 + nt * 16 + n16) * 64 + f * 32 + quad * 8);

    // QK (swapped) + in-register softmax -> pa[qt][fr] (fr = 32-kv fragment)
    short8 pa[2][4];
#pragma unroll
    for (int qt = 0; qt < 2; qt++) {
      floatx4 T[8];
#pragma unroll
      for (int nt = 0; nt < 8; nt++) {
        floatx4 s_ = (floatx4){0.f, 0.f, 0.f, 0.f};
        s_ = MFMA(kf[nt][0], qa[qt][0], s_);
        T[nt] = MFMA(kf[nt][1], qa[qt][1], s_);
      }
      unsigned u[8][2];
#pragma unroll
      for (int nt = 0; nt < 8; nt++) {
        float p0 = __expf(T[nt][0]);
        float p1 = __expf(T[nt][1]);
        float p2 = __expf(T[nt][2]);
        float p3 = __expf(T[nt][3]);
        l[qt] += (p0 + p1) + (p2 + p3);
        u[nt][0] = pk2(p0, p1);
        u[nt][1] = pk2(p2, p3);
      }
#pragma unroll
      for (int fr = 0; fr < 4; fr++) {
        unsigned a0 = (unsigned)__shfl((int)u[2 * fr + 0][0], srcA);
        unsigned a1 = (unsigned)__shfl((int)u[2 * fr + 1][0], srcA);
        unsigned b0 = (unsigned)__shfl((int)u[2 * fr + 0][1], srcA);
        unsigned b1 = (unsigned)__shfl((int)u[2 * fr + 1][1], srcA);
        unsigned c0 = (unsigned)__shfl((int)u[2 * fr + 0][0], srcB);
        unsigned c1 = (unsigned)__shfl((int)u[2 * fr + 1][0], srcB);
        unsigned d0 = (unsigned)__shfl((int)u[2 * fr + 0][1], srcB);
        unsigned d1 = (unsigned)__shfl((int)u[2 * fr + 1][1], srcB);
        uint4 wv;
        wv.x = qhi ? a1 : a0;
        wv.y = qhi ? b1 : b0;
        wv.z = qhi ? c1 : c0;
        wv.w = qhi ? d1 : d0;
        pa[qt][fr] = __builtin_bit_cast(short8, wv);
      }
    }

    // PV in two 64-kv halves (vv reused; WAR orders loads after consumption)
#pragma unroll
    for (int half = 0; half < 2; half++) {
#pragma unroll
      for (int nd = 0; nd < 4; nd++) {
        const short* vs = Vp + (size_t)(nd * 16 + n16) * 1024 + k0 +
                          half * 64 + quad * 8;
        vv[nd][0] = *reinterpret_cast<const short8*>(vs);
        vv[nd][1] = *reinterpret_cast<const short8*>(vs + 32);
      }
      __builtin_amdgcn_s_setprio(1);
#pragma unroll
      for (int qt = 0; qt < 2; qt++)
#pragma unroll
        for (int nd = 0; nd < 4; nd++) {
          O[qt][nd] = MFMA(pa[qt][2 * half + 0], vv[nd][0], O[qt][nd]);
          O[qt][nd] = MFMA(pa[qt][2 * half + 1], vv[nd][1], O[qt][nd]);
        }
      __builtin_amdgcn_s_setprio(0);
    }
  }

  // epilogue: l is per-q (q=n16), spread over quads -> reduce over quads,
  // then each lane fetches l for its output rows q=quad*4+r via shfl.
  for (int qt = 0; qt < 2; qt++) {
    float s = l[qt];
    s += __shfl_xor(s, 16);
    s += __shfl_xor(s, 32);
    for (int nd = 0; nd < 4; nd++)
      for (int r = 0; r < 4; r++) {
        float linv = 1.0f / __shfl(s, quad * 4 + r);
        int q = q0 + qt * 16 + quad * 4 + r;
        int ch = h * 64 + nd * 16 + n16;
        attnT[((size_t)b * 1024 + q) * 512 + ch] = f2bs(O[qt][nd][r] * linv);
      }
  }
}

// ---------------------------------------------------------------------------
// Kernel 4: projection GEMM + bias + residual, 64x64 tiles (r7, kept).
// ---------------------------------------------------------------------------
__global__ __launch_bounds__(256) void gemm_out(
    const short* __restrict__ Wb, const short* __restrict__ Xt,
    const float* __restrict__ bias, const float* __restrict__ resid,
    float* __restrict__ out) {
  __shared__ short As[2][2048];   // 64 rows x 32 k
  __shared__ short Bs[2][2048];
  int bx = blockIdx.x, by = blockIdx.y, bb = blockIdx.z;
  int m0 = by * 64, n0 = bx * 64;
  int t = threadIdx.x;
  int w = t >> 6, lane = t & 63, n16 = lane & 15, quad = lane >> 4;
  int wm = (w >> 1) * 32, wn = (w & 1) * 32;

  const short* Wa = Wb + (size_t)(m0 + (t >> 2)) * 512 + (t & 3) * 8;
  const short* Xa = Xt + (size_t)bb * 1024 * 512 +
                    (size_t)(n0 + (t >> 2)) * 512 + (t & 3) * 8;

#define STAGE(buf, kk)                                                \
  do {                                                                \
    glds16(Wa + (kk), &As[buf][t * 8]);                               \
    glds16(Xa + (kk), &Bs[buf][t * 8]);                               \
  } while (0)

  floatx4 acc[2][2];
  for (int i = 0; i < 2; i++)
    for (int j = 0; j < 2; j++) acc[i][j] = (floatx4){0.f, 0.f, 0.f, 0.f};

  STAGE(0, 0);
#pragma unroll 1
  for (int ks = 0; ks < 16; ks++) {
    int cur = ks & 1;
    __syncthreads();
    if (ks < 15) STAGE(cur ^ 1, (ks + 1) * 32);
    short8 a[2], b[2];
    for (int im = 0; im < 2; im++)
      a[im] = *reinterpret_cast<const short8*>(
          &As[cur][(wm + im * 16 + n16) * 32 + quad * 8]);
    for (int in = 0; in < 2; in++)
      b[in] = *reinterpret_cast<const short8*>(
          &Bs[cur][(wn + in * 16 + n16) * 32 + quad * 8]);
    for (int im = 0; im < 2; im++)
      for (int in = 0; in < 2; in++)
        acc[im][in] = MFMA(a[im], b[in], acc[im][in]);
  }
#undef STAGE

  for (int im = 0; im < 2; im++) {
    int m = m0 + wm + im * 16 + quad * 4;
    float4 bi = *reinterpret_cast<const float4*>(&bias[m]);
    for (int in = 0; in < 2; in++) {
      int nn = n0 + wn + in * 16 + n16;
      size_t idx = ((size_t)bb * 512 + m) * 1024 + nn;
      out[idx]        = acc[im][in][0] + bi.x + resid[idx];
      out[idx + 1024] = acc[im][in][1] + bi.y + resid[idx + 1024];
      out[idx + 2048] = acc[im][in][2] + bi.z + resid[idx + 2048];
      out[idx + 3072] = acc[im][in][3] + bi.w + resid[idx + 3072];
    }
  }
}

// ---------------------------------------------------------------------------
extern "C" void kernel_launch(void* const* d_in, const int* in_sizes, int n_in,
                              void* d_out, int out_size, void* d_ws, size_t ws_size,
                              hipStream_t stream) {
  const float* x     = (const float*)d_in[0];
  const float* gamma = (const float*)d_in[1];
  const float* beta  = (const float*)d_in[2];
  const float* w_in  = (const float*)d_in[3];
  const float* b_in  = (const float*)d_in[4];
  const float* w_out = (const float*)d_in[5];
  const float* b_out = (const float*)d_in[6];
  float* out = (float*)d_out;

  char* ws = (char*)d_ws;
  short* ht    = (short*)ws;                    //  8 MiB [8][1024][512]
  short* Qt    = (short*)(ws + (8u  << 20));    //  8 MiB [64][1024][64]
  short* Kt    = (short*)(ws + (16u << 20));    //  8 MiB [64][1024][64]
  short* Vn    = (short*)(ws + (24u << 20));    //  8 MiB [8][512][1024]
  short* attnT = (short*)(ws + (32u << 20));    //  8 MiB [8][1024][512]
  short* wbf1  = (short*)(ws + (40u << 20));    //  1.5 MiB
  short* wbf2  = (short*)(ws + (42u << 20));    //  0.5 MiB

  gn_cast_fused<<<1280, 256, 0, stream>>>(x, gamma, beta, ht,
                                          w_in, wbf1, w_out, wbf2);
  gemm_qkv<<<dim3(8, 12, B_), 256, 0, stream>>>(wbf1, ht, b_in, Qt, Kt, Vn);
  attn_mfma<<<512, 256, 0, stream>>>(Qt, Kt, Vn, attnT);
  gemm_out<<<dim3(16, 8, B_), 256, 0, stream>>>(wbf2, attnT, b_out, x, out);
}

// Round 14
// 161.129 us; speedup vs baseline: 1.1783x; 1.1457x over previous
//
#include <hip/hip_runtime.h>
#include <hip/hip_bf16.h>

// Problem dims (fixed by reference)
#define B_    8
#define C_    512
#define HW_   1024     // H*W = 32*32
#define NG    32
#define GCH   16
#define EPSV  1e-6f

typedef __attribute__((ext_vector_type(8))) short short8;   // 8 bf16 (4 VGPRs)
typedef __attribute__((ext_vector_type(4))) short short4v;  // 4 bf16
typedef __attribute__((ext_vector_type(4))) float floatx4;  // MFMA C/D

static __device__ __forceinline__ short f2bs(float f) {
  return __builtin_bit_cast(short, __float2bfloat16(f));
}
static __device__ __forceinline__ short4v pack4(float a, float b, float c, float d) {
  return (short4v){f2bs(a), f2bs(b), f2bs(c), f2bs(d)};
}
static __device__ __forceinline__ unsigned pk2(float a, float b) {
  return (unsigned)(unsigned short)f2bs(a) |
         ((unsigned)(unsigned short)f2bs(b) << 16);
}
#define MFMA(a, b, c) __builtin_amdgcn_mfma_f32_16x16x32_bf16((a), (b), (c), 0, 0, 0)

// async global->LDS, 16 B per lane (global_load_lds_dwordx4)
static __device__ __forceinline__ void glds16(const short* g, short* l) {
  __builtin_amdgcn_global_load_lds(
      (const __attribute__((address_space(1))) void*)g,
      (__attribute__((address_space(3))) void*)l, 16, 0, 0);
}

// ---------------------------------------------------------------------------
// Kernel 1 (fused): GroupNorm stats+apply+transpose AND both weight casts.
// (unchanged from r13 -- proven)
// ---------------------------------------------------------------------------
__global__ __launch_bounds__(256) void gn_cast_fused(
    const float* __restrict__ x, const float* __restrict__ gamma,
    const float* __restrict__ beta, short* __restrict__ ht,
    const float* __restrict__ w_in, short* __restrict__ wbf1,
    const float* __restrict__ w_out, short* __restrict__ wbf2) {
  int blk = blockIdx.x;
  int t = threadIdx.x;

  if (blk >= 256) {                      // ---- weight cast blocks ----
    int i = (blk - 256) * 256 + t;       // 262144 float4s total
    const float* s; short* d; int j;
    if (i < 196608) { s = w_in; d = wbf1; j = i; }
    else            { s = w_out; d = wbf2; j = i - 196608; }
    float4 v = reinterpret_cast<const float4*>(s)[j];
    reinterpret_cast<short4v*>(d)[j] = pack4(v.x, v.y, v.z, v.w);
    return;
  }

  // ---- GroupNorm block: (b, g) ----
  int b = blk >> 5, g = blk & 31;
  const float* xp = x + ((size_t)(b * C_) + g * GCH) * HW_;  // 16 ch x 1024

  __shared__ float Ls[4 * 1040];         // 4 subtiles of [16][65]  16.6 KB
  __shared__ float rs_[4], rss_[4], st_[2];

  // phase 1: stats over 16384 elements (16 f4 per thread, coalesced)
  float s = 0.f, ss = 0.f;
  for (int i = 0; i < 16; i++) {
    float4 v = *reinterpret_cast<const float4*>(xp + (t + i * 256) * 4);
    s  += (v.x + v.y) + (v.z + v.w);
    ss += (v.x * v.x + v.y * v.y) + (v.z * v.z + v.w * v.w);
  }
  for (int o = 32; o > 0; o >>= 1) {
    s  += __shfl_down(s, o);
    ss += __shfl_down(ss, o);
  }
  int wid = t >> 6, lane = t & 63;
  if (lane == 0) { rs_[wid] = s; rss_[wid] = ss; }
  __syncthreads();
  if (t == 0) {
    float stot  = rs_[0] + rs_[1] + rs_[2] + rs_[3];
    float sstot = rss_[0] + rss_[1] + rss_[2] + rss_[3];
    float mean = stot / 16384.f;
    float var  = sstot / 16384.f - mean * mean;
    st_[0] = mean;
    st_[1] = rsqrtf(var + EPSV);
  }
  __syncthreads();

  int r = t >> 4, c4 = t & 15;
  int ch = g * GCH + r;
  float ga = gamma[ch] * st_[1];
  float be = beta[ch] - st_[0] * ga;
  int sq = t >> 2, cq = t & 3;

  // phase 2: 4 outer iters x 4 subtiles; x re-read (L2-hot), transpose, write
  for (int it = 0; it < 4; it++) {
    for (int sub = 0; sub < 4; sub++) {
      int s0 = (it * 4 + sub) * 64;
      float4 v = *reinterpret_cast<const float4*>(xp + r * HW_ + s0 + c4 * 4);
      float* L = Ls + sub * 1040;
      L[r * 65 + c4 * 4 + 0] = v.x * ga + be;
      L[r * 65 + c4 * 4 + 1] = v.y * ga + be;
      L[r * 65 + c4 * 4 + 2] = v.z * ga + be;
      L[r * 65 + c4 * 4 + 3] = v.w * ga + be;
    }
    __syncthreads();
    for (int sub = 0; sub < 4; sub++) {
      int s0 = (it * 4 + sub) * 64;
      const float* L = Ls + sub * 1040;
      float a0 = L[(cq * 4 + 0) * 65 + sq];
      float a1 = L[(cq * 4 + 1) * 65 + sq];
      float a2 = L[(cq * 4 + 2) * 65 + sq];
      float a3 = L[(cq * 4 + 3) * 65 + sq];
      *reinterpret_cast<short4v*>(
          ht + ((size_t)b * 1024 + s0 + sq) * 512 + g * GCH + cq * 4) =
          pack4(a0, a1, a2, a3);
    }
    __syncthreads();
  }
}

// ---------------------------------------------------------------------------
// Kernel 2: QKV GEMM, m97 structure (unchanged from r6 -- proven).
// ---------------------------------------------------------------------------
__global__ __launch_bounds__(256) void gemm_qkv(
    const short* __restrict__ Wb, const short* __restrict__ ht,
    const float* __restrict__ bias,
    short* __restrict__ Qt, short* __restrict__ Kt, short* __restrict__ Vn) {
  __shared__ short As[2][4096];   // [buf][row*32 + k]  128 rows x 32 k
  __shared__ short Bs[2][4096];
  int bx = blockIdx.x, by = blockIdx.y, bb = blockIdx.z;
  int m0 = by * 128, n0 = bx * 128;
  int t = threadIdx.x;
  int w = t >> 6, lane = t & 63, n16 = lane & 15, quad = lane >> 4;
  int wm = (w >> 1) * 64, wn = (w & 1) * 64;

  const short* Wa = Wb + (size_t)(m0 + (t >> 2)) * 512 + (t & 3) * 8;
  const short* Xa = ht + (size_t)bb * 1024 * 512 +
                    (size_t)(n0 + (t >> 2)) * 512 + (t & 3) * 8;

#define STAGE(buf, kk)                                                \
  do {                                                                \
    glds16(Wa + (kk), &As[buf][t * 8]);                               \
    glds16(Wa + 64 * 512 + (kk), &As[buf][2048 + t * 8]);             \
    glds16(Xa + (kk), &Bs[buf][t * 8]);                               \
    glds16(Xa + 64 * 512 + (kk), &Bs[buf][2048 + t * 8]);             \
  } while (0)

  floatx4 acc[4][4];
  for (int i = 0; i < 4; i++)
    for (int j = 0; j < 4; j++) acc[i][j] = (floatx4){0.f, 0.f, 0.f, 0.f};

  STAGE(0, 0);
#pragma unroll 1
  for (int ks = 0; ks < 16; ks++) {
    int cur = ks & 1;
    __syncthreads();                       // drains staging + prior ds_reads
    if (ks < 15) STAGE(cur ^ 1, (ks + 1) * 32);
    short8 a[4], b[4];
    for (int im = 0; im < 4; im++)
      a[im] = *reinterpret_cast<const short8*>(
          &As[cur][(wm + im * 16 + n16) * 32 + quad * 8]);
    for (int in = 0; in < 4; in++)
      b[in] = *reinterpret_cast<const short8*>(
          &Bs[cur][(wn + in * 16 + n16) * 32 + quad * 8]);
    for (int im = 0; im < 4; im++)
      for (int in = 0; in < 4; in++)
        acc[im][in] = MFMA(a[im], b[in], acc[im][in]);
  }
#undef STAGE

  if (m0 < 1024) {                 // Q or K: transposed store [seq][d]
    const bool isQ = (m0 < 512);
    short* base = isQ ? Qt : Kt;
    const float sc = isQ ? 0.125f : 1.0f;   // fold 1/sqrt(64) into Q
    for (int im = 0; im < 4; im++) {
      int m = m0 + wm + im * 16 + quad * 4;
      int hh = (m >> 6) & 7, d0 = m & 63;
      float4 bi = *reinterpret_cast<const float4*>(&bias[m]);
      short* hb = base + (size_t)(bb * 8 + hh) * 1024 * 64 + d0;
      for (int in = 0; in < 4; in++) {
        int nn = n0 + wn + in * 16 + n16;
        *reinterpret_cast<short4v*>(hb + (size_t)nn * 64) =
            pack4((acc[im][in][0] + bi.x) * sc, (acc[im][in][1] + bi.y) * sc,
                  (acc[im][in][2] + bi.z) * sc, (acc[im][in][3] + bi.w) * sc);
      }
    }
  } else {                         // V: natural store [ch][seq]
    for (int im = 0; im < 4; im++) {
      int m = m0 + wm + im * 16 + quad * 4;
      float4 bi = *reinterpret_cast<const float4*>(&bias[m]);
      int ch = m - 1024;
      for (int in = 0; in < 4; in++) {
        int nn = n0 + wn + in * 16 + n16;
        short* vp = Vn + (size_t)(bb * 512 + ch) * 1024 + nn;
        vp[0]    = f2bs(acc[im][in][0] + bi.x);
        vp[1024] = f2bs(acc[im][in][1] + bi.y);
        vp[2048] = f2bs(acc[im][in][2] + bi.z);
        vp[3072] = f2bs(acc[im][in][3] + bi.w);
      }
    }
  }
}

// ---------------------------------------------------------------------------
// Kernel 3: attention v10 -- r9 swapped-QK/in-reg-softmax compute + LDS
//   K/V staging via global_load_lds (m97 pattern).
//   13-round diagnosis: at VGPR~108 the allocator keeps 1-2 in-register
//   loads in flight -> 256 serialized ~280cy L2 trips/wave = the whole wall.
//   global_load_lds is VGPR-FREE (vmcnt-counted): all staging loads fly
//   concurrently, and one LDS copy serves all 4 waves (4x less L2 traffic).
//   Bank fix (rule 21, both-sides-or-neither): [64][64]bf16 tile at 128B row
//   stride is 16-way conflicted; staged with inverse-XOR-swizzled per-lane
//   GLOBAL source (LDS dest linear, as glds requires) and read with
//   colb ^ ((row&7)<<4).  Verified both directions on a concrete element.
// ---------------------------------------------------------------------------
__global__ __launch_bounds__(256) void attn_mfma(
    const short* __restrict__ Qt, const short* __restrict__ Kt,
    const short* __restrict__ Vn, short* __restrict__ attnT) {
  __shared__ short KT[2][4096];   // [buf][64 rows][64 d]  8 KB per buf
  __shared__ short VT[2][4096];   // [buf][64 ch][64 kv]
  int blk0 = blockIdx.x;
  int blk = (blk0 & 7) * 64 + (blk0 >> 3);   // 512 = 8 XCD x 64: batch->XCD
  int qb = blk & 7, h = (blk >> 3) & 7, b = blk >> 6;
  int t = threadIdx.x;
  int w = t >> 6, lane = t & 63, n16 = lane & 15, quad = lane >> 4;
  int q0 = qb * 128 + w * 32;
  int qhi = quad >> 1;
  int srcA = ((quad & 1) << 5) + n16;
  int srcB = srcA + 16;

  const short* Qp = Qt + (size_t)(b * 8 + h) * 1024 * 64;
  const short* Kp = Kt + (size_t)(b * 8 + h) * 1024 * 64;
  const short* Vp = Vn + (size_t)(b * 512 + h * 64) * 1024;

  short8 qa[2][2];
  for (int qt = 0; qt < 2; qt++)
    for (int f = 0; f < 2; f++)
      qa[qt][f] = *reinterpret_cast<const short8*>(
          Qp + (size_t)(q0 + qt * 16 + n16) * 64 + f * 32 + quad * 8);

  floatx4 O[2][4];
  float l[2] = {0.f, 0.f};
  for (int qt = 0; qt < 2; qt++)
    for (int i = 0; i < 4; i++) O[qt][i] = (floatx4){0.f, 0.f, 0.f, 0.f};

  // staging chunk geometry (per thread: 2 chunks of 16 B per tile)
  int p0 = t * 16, p1 = 4096 + t * 16;           // LDS byte offsets
  int r0 = p0 >> 7, c0 = (p0 & 127) ^ ((r0 & 7) << 4);
  int r1 = p1 >> 7, c1 = (p1 & 127) ^ ((r1 & 7) << 4);

#define STAGEKV(buf, ktv)                                                    \
  do {                                                                       \
    const char* Kb_ = (const char*)Kp + (ktv) * 8192;                        \
    const char* Vb_ = (const char*)Vp + (ktv) * 128;                         \
    glds16((const short*)(Kb_ + r0 * 128 + c0), &KT[buf][p0 >> 1]);          \
    glds16((const short*)(Kb_ + r1 * 128 + c1), &KT[buf][p1 >> 1]);          \
    glds16((const short*)(Vb_ + (size_t)r0 * 2048 + c0), &VT[buf][p0 >> 1]); \
    glds16((const short*)(Vb_ + (size_t)r1 * 2048 + c1), &VT[buf][p1 >> 1]); \
  } while (0)

// swizzled LDS byte offset for a 16B read at (row, colbyte)
#define LDSOFF(row, colb) ((row) * 128 + (((colb) ^ (((row) & 7) << 4))))

#define BODY(cur)                                                            \
  do {                                                                       \
    short8 kf_[4][2], v_[4][2];                                              \
    _Pragma("unroll")                                                        \
    for (int nt_ = 0; nt_ < 4; nt_++)                                        \
      _Pragma("unroll")                                                      \
      for (int f_ = 0; f_ < 2; f_++) {                                       \
        kf_[nt_][f_] = *reinterpret_cast<const short8*>(                     \
            (const char*)&KT[cur][0] +                                       \
            LDSOFF(nt_ * 16 + n16, f_ * 64 + quad * 16));                    \
        v_[nt_][f_] = *reinterpret_cast<const short8*>(                      \
            (const char*)&VT[cur][0] +                                       \
            LDSOFF(nt_ * 16 + n16, f_ * 64 + quad * 16));                    \
      }                                                                      \
    _Pragma("unroll")                                                        \
    for (int qt_ = 0; qt_ < 2; qt_++) {                                      \
      floatx4 T_[4];                                                         \
      _Pragma("unroll")                                                      \
      for (int nt_ = 0; nt_ < 4; nt_++) {                                    \
        floatx4 s_ = (floatx4){0.f, 0.f, 0.f, 0.f};                          \
        s_ = MFMA(kf_[nt_][0], qa[qt_][0], s_);                              \
        T_[nt_] = MFMA(kf_[nt_][1], qa[qt_][1], s_);                         \
      }                                                                      \
      unsigned u_[4][2];                                                     \
      _Pragma("unroll")                                                      \
      for (int nt_ = 0; nt_ < 4; nt_++) {                                    \
        float p0_ = __expf(T_[nt_][0]);                                      \
        float p1_ = __expf(T_[nt_][1]);                                      \
        float p2_ = __expf(T_[nt_][2]);                                      \
        float p3_ = __expf(T_[nt_][3]);                                      \
        l[qt_] += (p0_ + p1_) + (p2_ + p3_);                                 \
        u_[nt_][0] = pk2(p0_, p1_);                                          \
        u_[nt_][1] = pk2(p2_, p3_);                                          \
      }                                                                      \
      short8 pa_[2];                                                         \
      _Pragma("unroll")                                                      \
      for (int f_ = 0; f_ < 2; f_++) {                                       \
        unsigned a0_ = (unsigned)__shfl((int)u_[2 * f_ + 0][0], srcA);       \
        unsigned a1_ = (unsigned)__shfl((int)u_[2 * f_ + 1][0], srcA);       \
        unsigned b0_ = (unsigned)__shfl((int)u_[2 * f_ + 0][1], srcA);       \
        unsigned b1_ = (unsigned)__shfl((int)u_[2 * f_ + 1][1], srcA);       \
        unsigned c0_ = (unsigned)__shfl((int)u_[2 * f_ + 0][0], srcB);       \
        unsigned c1_ = (unsigned)__shfl((int)u_[2 * f_ + 1][0], srcB);       \
        unsigned d0_ = (unsigned)__shfl((int)u_[2 * f_ + 0][1], srcB);       \
        unsigned d1_ = (unsigned)__shfl((int)u_[2 * f_ + 1][1], srcB);       \
        uint4 wv_;                                                           \
        wv_.x = qhi ? a1_ : a0_;                                             \
        wv_.y = qhi ? b1_ : b0_;                                             \
        wv_.z = qhi ? c1_ : c0_;                                             \
        wv_.w = qhi ? d1_ : d0_;                                             \
        pa_[f_] = __builtin_bit_cast(short8, wv_);                           \
      }                                                                      \
      __builtin_amdgcn_s_setprio(1);                                         \
      _Pragma("unroll")                                                      \
      for (int nd_ = 0; nd_ < 4; nd_++) {                                    \
        O[qt_][nd_] = MFMA(pa_[0], v_[nd_][0], O[qt_][nd_]);                 \
        O[qt_][nd_] = MFMA(pa_[1], v_[nd_][1], O[qt_][nd_]);                 \
      }                                                                      \
      __builtin_amdgcn_s_setprio(0);                                         \
    }                                                                        \
  } while (0)

  STAGEKV(0, 0);
#pragma unroll 1
  for (int kt = 0; kt < 16; kt++) {
    int cur = kt & 1;
    __syncthreads();                       // drains staging + prior ds_reads
    if (kt < 15) STAGEKV(cur ^ 1, kt + 1);
    BODY(cur);
  }
#undef STAGEKV
#undef LDSOFF
#undef BODY

  // epilogue: l is per-q (q=n16), spread over quads -> reduce over quads,
  // then each lane fetches l for its output rows q=quad*4+r via shfl.
  for (int qt = 0; qt < 2; qt++) {
    float s = l[qt];
    s += __shfl_xor(s, 16);
    s += __shfl_xor(s, 32);
    for (int nd = 0; nd < 4; nd++)
      for (int r = 0; r < 4; r++) {
        float linv = 1.0f / __shfl(s, quad * 4 + r);
        int q = q0 + qt * 16 + quad * 4 + r;
        int ch = h * 64 + nd * 16 + n16;
        attnT[((size_t)b * 1024 + q) * 512 + ch] = f2bs(O[qt][nd][r] * linv);
      }
  }
}

// ---------------------------------------------------------------------------
// Kernel 4: projection GEMM + bias + residual, 64x64 tiles (r7, kept).
// ---------------------------------------------------------------------------
__global__ __launch_bounds__(256) void gemm_out(
    const short* __restrict__ Wb, const short* __restrict__ Xt,
    const float* __restrict__ bias, const float* __restrict__ resid,
    float* __restrict__ out) {
  __shared__ short As[2][2048];   // 64 rows x 32 k
  __shared__ short Bs[2][2048];
  int bx = blockIdx.x, by = blockIdx.y, bb = blockIdx.z;
  int m0 = by * 64, n0 = bx * 64;
  int t = threadIdx.x;
  int w = t >> 6, lane = t & 63, n16 = lane & 15, quad = lane >> 4;
  int wm = (w >> 1) * 32, wn = (w & 1) * 32;

  const short* Wa = Wb + (size_t)(m0 + (t >> 2)) * 512 + (t & 3) * 8;
  const short* Xa = Xt + (size_t)bb * 1024 * 512 +
                    (size_t)(n0 + (t >> 2)) * 512 + (t & 3) * 8;

#define STAGE(buf, kk)                                                \
  do {                                                                \
    glds16(Wa + (kk), &As[buf][t * 8]);                               \
    glds16(Xa + (kk), &Bs[buf][t * 8]);                               \
  } while (0)

  floatx4 acc[2][2];
  for (int i = 0; i < 2; i++)
    for (int j = 0; j < 2; j++) acc[i][j] = (floatx4){0.f, 0.f, 0.f, 0.f};

  STAGE(0, 0);
#pragma unroll 1
  for (int ks = 0; ks < 16; ks++) {
    int cur = ks & 1;
    __syncthreads();
    if (ks < 15) STAGE(cur ^ 1, (ks + 1) * 32);
    short8 a[2], b[2];
    for (int im = 0; im < 2; im++)
      a[im] = *reinterpret_cast<const short8*>(
          &As[cur][(wm + im * 16 + n16) * 32 + quad * 8]);
    for (int in = 0; in < 2; in++)
      b[in] = *reinterpret_cast<const short8*>(
          &Bs[cur][(wn + in * 16 + n16) * 32 + quad * 8]);
    for (int im = 0; im < 2; im++)
      for (int in = 0; in < 2; in++)
        acc[im][in] = MFMA(a[im], b[in], acc[im][in]);
  }
#undef STAGE

  for (int im = 0; im < 2; im++) {
    int m = m0 + wm + im * 16 + quad * 4;
    float4 bi = *reinterpret_cast<const float4*>(&bias[m]);
    for (int in = 0; in < 2; in++) {
      int nn = n0 + wn + in * 16 + n16;
      size_t idx = ((size_t)bb * 512 + m) * 1024 + nn;
      out[idx]        = acc[im][in][0] + bi.x + resid[idx];
      out[idx + 1024] = acc[im][in][1] + bi.y + resid[idx + 1024];
      out[idx + 2048] = acc[im][in][2] + bi.z + resid[idx + 2048];
      out[idx + 3072] = acc[im][in][3] + bi.w + resid[idx + 3072];
    }
  }
}

// ---------------------------------------------------------------------------
extern "C" void kernel_launch(void* const* d_in, const int* in_sizes, int n_in,
                              void* d_out, int out_size, void* d_ws, size_t ws_size,
                              hipStream_t stream) {
  const float* x     = (const float*)d_in[0];
  const float* gamma = (const float*)d_in[1];
  const float* beta  = (const float*)d_in[2];
  const float* w_in  = (const float*)d_in[3];
  const float* b_in  = (const float*)d_in[4];
  const float* w_out = (const float*)d_in[5];
  const float* b_out = (const float*)d_in[6];
  float* out = (float*)d_out;

  char* ws = (char*)d_ws;
  short* ht    = (short*)ws;                    //  8 MiB [8][1024][512]
  short* Qt    = (short*)(ws + (8u  << 20));    //  8 MiB [64][1024][64]
  short* Kt    = (short*)(ws + (16u << 20));    //  8 MiB [64][1024][64]
  short* Vn    = (short*)(ws + (24u << 20));    //  8 MiB [8][512][1024]
  short* attnT = (short*)(ws + (32u << 20));    //  8 MiB [8][1024][512]
  short* wbf1  = (short*)(ws + (40u << 20));    //  1.5 MiB
  short* wbf2  = (short*)(ws + (42u << 20));    //  0.5 MiB

  gn_cast_fused<<<1280, 256, 0, stream>>>(x, gamma, beta, ht,
                                          w_in, wbf1, w_out, wbf2);
  gemm_qkv<<<dim3(8, 12, B_), 256, 0, stream>>>(wbf1, ht, b_in, Qt, Kt, Vn);
  attn_mfma<<<512, 256, 0, stream>>>(Qt, Kt, Vn, attnT);
  gemm_out<<<dim3(16, 8, B_), 256, 0, stream>>>(wbf2, attnT, b_out, x, out);
}

// Round 15
// 159.533 us; speedup vs baseline: 1.1901x; 1.0100x over previous
//
#include <hip/hip_runtime.h>
#include <hip/hip_bf16.h>

// Problem dims (fixed by reference)
#define B_    8
#define C_    512
#define HW_   1024     // H*W = 32*32
#define NG    32
#define GCH   16
#define EPSV  1e-6f

typedef __attribute__((ext_vector_type(8))) short short8;   // 8 bf16 (4 VGPRs)
typedef __attribute__((ext_vector_type(4))) short short4v;  // 4 bf16
typedef __attribute__((ext_vector_type(4))) float floatx4;  // MFMA C/D

static __device__ __forceinline__ short f2bs(float f) {
  return __builtin_bit_cast(short, __float2bfloat16(f));
}
static __device__ __forceinline__ short4v pack4(float a, float b, float c, float d) {
  return (short4v){f2bs(a), f2bs(b), f2bs(c), f2bs(d)};
}
static __device__ __forceinline__ unsigned pk2(float a, float b) {
  return (unsigned)(unsigned short)f2bs(a) |
         ((unsigned)(unsigned short)f2bs(b) << 16);
}
#define MFMA(a, b, c) __builtin_amdgcn_mfma_f32_16x16x32_bf16((a), (b), (c), 0, 0, 0)

// async global->LDS, 16 B per lane (global_load_lds_dwordx4)
static __device__ __forceinline__ void glds16(const short* g, short* l) {
  __builtin_amdgcn_global_load_lds(
      (const __attribute__((address_space(1))) void*)g,
      (__attribute__((address_space(3))) void*)l, 16, 0, 0);
}

// ---------------------------------------------------------------------------
// Kernel 1 (fused): GroupNorm stats+apply+transpose AND both weight casts.
// (unchanged from r13 -- proven)
// ---------------------------------------------------------------------------
__global__ __launch_bounds__(256) void gn_cast_fused(
    const float* __restrict__ x, const float* __restrict__ gamma,
    const float* __restrict__ beta, short* __restrict__ ht,
    const float* __restrict__ w_in, short* __restrict__ wbf1,
    const float* __restrict__ w_out, short* __restrict__ wbf2) {
  int blk = blockIdx.x;
  int t = threadIdx.x;

  if (blk >= 256) {                      // ---- weight cast blocks ----
    int i = (blk - 256) * 256 + t;       // 262144 float4s total
    const float* s; short* d; int j;
    if (i < 196608) { s = w_in; d = wbf1; j = i; }
    else            { s = w_out; d = wbf2; j = i - 196608; }
    float4 v = reinterpret_cast<const float4*>(s)[j];
    reinterpret_cast<short4v*>(d)[j] = pack4(v.x, v.y, v.z, v.w);
    return;
  }

  // ---- GroupNorm block: (b, g) ----
  int b = blk >> 5, g = blk & 31;
  const float* xp = x + ((size_t)(b * C_) + g * GCH) * HW_;  // 16 ch x 1024

  __shared__ float Ls[4 * 1040];         // 4 subtiles of [16][65]  16.6 KB
  __shared__ float rs_[4], rss_[4], st_[2];

  // phase 1: stats over 16384 elements (16 f4 per thread, coalesced)
  float s = 0.f, ss = 0.f;
  for (int i = 0; i < 16; i++) {
    float4 v = *reinterpret_cast<const float4*>(xp + (t + i * 256) * 4);
    s  += (v.x + v.y) + (v.z + v.w);
    ss += (v.x * v.x + v.y * v.y) + (v.z * v.z + v.w * v.w);
  }
  for (int o = 32; o > 0; o >>= 1) {
    s  += __shfl_down(s, o);
    ss += __shfl_down(ss, o);
  }
  int wid = t >> 6, lane = t & 63;
  if (lane == 0) { rs_[wid] = s; rss_[wid] = ss; }
  __syncthreads();
  if (t == 0) {
    float stot  = rs_[0] + rs_[1] + rs_[2] + rs_[3];
    float sstot = rss_[0] + rss_[1] + rss_[2] + rss_[3];
    float mean = stot / 16384.f;
    float var  = sstot / 16384.f - mean * mean;
    st_[0] = mean;
    st_[1] = rsqrtf(var + EPSV);
  }
  __syncthreads();

  int r = t >> 4, c4 = t & 15;
  int ch = g * GCH + r;
  float ga = gamma[ch] * st_[1];
  float be = beta[ch] - st_[0] * ga;
  int sq = t >> 2, cq = t & 3;

  // phase 2: 4 outer iters x 4 subtiles; x re-read (L2-hot), transpose, write
  for (int it = 0; it < 4; it++) {
    for (int sub = 0; sub < 4; sub++) {
      int s0 = (it * 4 + sub) * 64;
      float4 v = *reinterpret_cast<const float4*>(xp + r * HW_ + s0 + c4 * 4);
      float* L = Ls + sub * 1040;
      L[r * 65 + c4 * 4 + 0] = v.x * ga + be;
      L[r * 65 + c4 * 4 + 1] = v.y * ga + be;
      L[r * 65 + c4 * 4 + 2] = v.z * ga + be;
      L[r * 65 + c4 * 4 + 3] = v.w * ga + be;
    }
    __syncthreads();
    for (int sub = 0; sub < 4; sub++) {
      int s0 = (it * 4 + sub) * 64;
      const float* L = Ls + sub * 1040;
      float a0 = L[(cq * 4 + 0) * 65 + sq];
      float a1 = L[(cq * 4 + 1) * 65 + sq];
      float a2 = L[(cq * 4 + 2) * 65 + sq];
      float a3 = L[(cq * 4 + 3) * 65 + sq];
      *reinterpret_cast<short4v*>(
          ht + ((size_t)b * 1024 + s0 + sq) * 512 + g * GCH + cq * 4) =
          pack4(a0, a1, a2, a3);
    }
    __syncthreads();
  }
}

// ---------------------------------------------------------------------------
// Kernel 2: QKV GEMM, m97 structure (unchanged from r6 -- proven).
// ---------------------------------------------------------------------------
__global__ __launch_bounds__(256) void gemm_qkv(
    const short* __restrict__ Wb, const short* __restrict__ ht,
    const float* __restrict__ bias,
    short* __restrict__ Qt, short* __restrict__ Kt, short* __restrict__ Vn) {
  __shared__ short As[2][4096];   // [buf][row*32 + k]  128 rows x 32 k
  __shared__ short Bs[2][4096];
  int bx = blockIdx.x, by = blockIdx.y, bb = blockIdx.z;
  int m0 = by * 128, n0 = bx * 128;
  int t = threadIdx.x;
  int w = t >> 6, lane = t & 63, n16 = lane & 15, quad = lane >> 4;
  int wm = (w >> 1) * 64, wn = (w & 1) * 64;

  const short* Wa = Wb + (size_t)(m0 + (t >> 2)) * 512 + (t & 3) * 8;
  const short* Xa = ht + (size_t)bb * 1024 * 512 +
                    (size_t)(n0 + (t >> 2)) * 512 + (t & 3) * 8;

#define STAGE(buf, kk)                                                \
  do {                                                                \
    glds16(Wa + (kk), &As[buf][t * 8]);                               \
    glds16(Wa + 64 * 512 + (kk), &As[buf][2048 + t * 8]);             \
    glds16(Xa + (kk), &Bs[buf][t * 8]);                               \
    glds16(Xa + 64 * 512 + (kk), &Bs[buf][2048 + t * 8]);             \
  } while (0)

  floatx4 acc[4][4];
  for (int i = 0; i < 4; i++)
    for (int j = 0; j < 4; j++) acc[i][j] = (floatx4){0.f, 0.f, 0.f, 0.f};

  STAGE(0, 0);
#pragma unroll 1
  for (int ks = 0; ks < 16; ks++) {
    int cur = ks & 1;
    __syncthreads();                       // drains staging + prior ds_reads
    if (ks < 15) STAGE(cur ^ 1, (ks + 1) * 32);
    short8 a[4], b[4];
    for (int im = 0; im < 4; im++)
      a[im] = *reinterpret_cast<const short8*>(
          &As[cur][(wm + im * 16 + n16) * 32 + quad * 8]);
    for (int in = 0; in < 4; in++)
      b[in] = *reinterpret_cast<const short8*>(
          &Bs[cur][(wn + in * 16 + n16) * 32 + quad * 8]);
    for (int im = 0; im < 4; im++)
      for (int in = 0; in < 4; in++)
        acc[im][in] = MFMA(a[im], b[in], acc[im][in]);
  }
#undef STAGE

  if (m0 < 1024) {                 // Q or K: transposed store [seq][d]
    const bool isQ = (m0 < 512);
    short* base = isQ ? Qt : Kt;
    const float sc = isQ ? 0.125f : 1.0f;   // fold 1/sqrt(64) into Q
    for (int im = 0; im < 4; im++) {
      int m = m0 + wm + im * 16 + quad * 4;
      int hh = (m >> 6) & 7, d0 = m & 63;
      float4 bi = *reinterpret_cast<const float4*>(&bias[m]);
      short* hb = base + (size_t)(bb * 8 + hh) * 1024 * 64 + d0;
      for (int in = 0; in < 4; in++) {
        int nn = n0 + wn + in * 16 + n16;
        *reinterpret_cast<short4v*>(hb + (size_t)nn * 64) =
            pack4((acc[im][in][0] + bi.x) * sc, (acc[im][in][1] + bi.y) * sc,
                  (acc[im][in][2] + bi.z) * sc, (acc[im][in][3] + bi.w) * sc);
      }
    }
  } else {                         // V: natural store [ch][seq]
    for (int im = 0; im < 4; im++) {
      int m = m0 + wm + im * 16 + quad * 4;
      float4 bi = *reinterpret_cast<const float4*>(&bias[m]);
      int ch = m - 1024;
      for (int in = 0; in < 4; in++) {
        int nn = n0 + wn + in * 16 + n16;
        short* vp = Vn + (size_t)(bb * 512 + ch) * 1024 + nn;
        vp[0]    = f2bs(acc[im][in][0] + bi.x);
        vp[1024] = f2bs(acc[im][in][1] + bi.y);
        vp[2048] = f2bs(acc[im][in][2] + bi.z);
        vp[3072] = f2bs(acc[im][in][3] + bi.w);
      }
    }
  }
}

// ---------------------------------------------------------------------------
// Kernel 3: attention v11 -- r14 LDS-staged body (the 13-round breakthrough:
//   VGPR-free glds staging), q-split 128 -> 64 rows/block.
//   r14 removed the register-load serialization that made occupancy useless
//   (r2/r7/r8); now co-resident blocks DO cover each other's barrier drains.
//   1024 blocks = 4 blocks/CU (LDS 32KB x 4 = 128 <= 160KB; VGPR ~90).
//   Same swizzled staging (rule 21 both-sides), same swapped-QK in-register
//   softmax, XCD remap extended bijectively to 1024 (batch k -> XCD k).
// ---------------------------------------------------------------------------
__global__ __launch_bounds__(256) void attn_mfma(
    const short* __restrict__ Qt, const short* __restrict__ Kt,
    const short* __restrict__ Vn, short* __restrict__ attnT) {
  __shared__ short KT[2][4096];   // [buf][64 rows][64 d]  8 KB per buf
  __shared__ short VT[2][4096];   // [buf][64 ch][64 kv]
  int blk0 = blockIdx.x;
  int blk = (blk0 & 7) * 128 + (blk0 >> 3);  // 1024 = 8 XCD x 128: batch->XCD
  int qb = blk & 15, h = (blk >> 4) & 7, b = blk >> 7;
  int t = threadIdx.x;
  int w = t >> 6, lane = t & 63, n16 = lane & 15, quad = lane >> 4;
  int q0 = qb * 64 + w * 16;
  int qhi = quad >> 1;
  int srcA = ((quad & 1) << 5) + n16;
  int srcB = srcA + 16;

  const short* Qp = Qt + (size_t)(b * 8 + h) * 1024 * 64;
  const short* Kp = Kt + (size_t)(b * 8 + h) * 1024 * 64;
  const short* Vp = Vn + (size_t)(b * 512 + h * 64) * 1024;

  short8 qa[2];
  for (int f = 0; f < 2; f++)
    qa[f] = *reinterpret_cast<const short8*>(
        Qp + (size_t)(q0 + n16) * 64 + f * 32 + quad * 8);

  floatx4 O[4];
  float l = 0.f;
  for (int i = 0; i < 4; i++) O[i] = (floatx4){0.f, 0.f, 0.f, 0.f};

  // staging chunk geometry (per thread: 2 chunks of 16 B per tile)
  int p0 = t * 16, p1 = 4096 + t * 16;           // LDS byte offsets
  int r0 = p0 >> 7, c0 = (p0 & 127) ^ ((r0 & 7) << 4);
  int r1 = p1 >> 7, c1 = (p1 & 127) ^ ((r1 & 7) << 4);

#define STAGEKV(buf, ktv)                                                    \
  do {                                                                       \
    const char* Kb_ = (const char*)Kp + (ktv) * 8192;                        \
    const char* Vb_ = (const char*)Vp + (ktv) * 128;                         \
    glds16((const short*)(Kb_ + r0 * 128 + c0), &KT[buf][p0 >> 1]);          \
    glds16((const short*)(Kb_ + r1 * 128 + c1), &KT[buf][p1 >> 1]);          \
    glds16((const short*)(Vb_ + (size_t)r0 * 2048 + c0), &VT[buf][p0 >> 1]); \
    glds16((const short*)(Vb_ + (size_t)r1 * 2048 + c1), &VT[buf][p1 >> 1]); \
  } while (0)

// swizzled LDS byte offset for a 16B read at (row, colbyte)
#define LDSOFF(row, colb) ((row) * 128 + (((colb) ^ (((row) & 7) << 4))))

  STAGEKV(0, 0);
#pragma unroll 1
  for (int kt = 0; kt < 16; kt++) {
    int cur = kt & 1;
    __syncthreads();                       // drains staging + prior ds_reads
    if (kt < 15) STAGEKV(cur ^ 1, kt + 1);

    short8 kf[4][2], v[4][2];
#pragma unroll
    for (int nt = 0; nt < 4; nt++)
#pragma unroll
      for (int f = 0; f < 2; f++) {
        kf[nt][f] = *reinterpret_cast<const short8*>(
            (const char*)&KT[cur][0] +
            LDSOFF(nt * 16 + n16, f * 64 + quad * 16));
        v[nt][f] = *reinterpret_cast<const short8*>(
            (const char*)&VT[cur][0] +
            LDSOFF(nt * 16 + n16, f * 64 + quad * 16));
      }

    floatx4 T[4];
#pragma unroll
    for (int nt = 0; nt < 4; nt++) {
      floatx4 s_ = (floatx4){0.f, 0.f, 0.f, 0.f};
      s_ = MFMA(kf[nt][0], qa[0], s_);
      T[nt] = MFMA(kf[nt][1], qa[1], s_);
    }
    unsigned u[4][2];
#pragma unroll
    for (int nt = 0; nt < 4; nt++) {
      float p0_ = __expf(T[nt][0]);
      float p1_ = __expf(T[nt][1]);
      float p2_ = __expf(T[nt][2]);
      float p3_ = __expf(T[nt][3]);
      l += (p0_ + p1_) + (p2_ + p3_);
      u[nt][0] = pk2(p0_, p1_);
      u[nt][1] = pk2(p2_, p3_);
    }
    short8 pa[2];
#pragma unroll
    for (int f = 0; f < 2; f++) {
      unsigned a0 = (unsigned)__shfl((int)u[2 * f + 0][0], srcA);
      unsigned a1 = (unsigned)__shfl((int)u[2 * f + 1][0], srcA);
      unsigned b0 = (unsigned)__shfl((int)u[2 * f + 0][1], srcA);
      unsigned b1 = (unsigned)__shfl((int)u[2 * f + 1][1], srcA);
      unsigned c0_ = (unsigned)__shfl((int)u[2 * f + 0][0], srcB);
      unsigned c1_ = (unsigned)__shfl((int)u[2 * f + 1][0], srcB);
      unsigned d0 = (unsigned)__shfl((int)u[2 * f + 0][1], srcB);
      unsigned d1 = (unsigned)__shfl((int)u[2 * f + 1][1], srcB);
      uint4 wv;
      wv.x = qhi ? a1 : a0;
      wv.y = qhi ? b1 : b0;
      wv.z = qhi ? c1_ : c0_;
      wv.w = qhi ? d1 : d0;
      pa[f] = __builtin_bit_cast(short8, wv);
    }
    __builtin_amdgcn_s_setprio(1);
#pragma unroll
    for (int nd = 0; nd < 4; nd++) {
      O[nd] = MFMA(pa[0], v[nd][0], O[nd]);
      O[nd] = MFMA(pa[1], v[nd][1], O[nd]);
    }
    __builtin_amdgcn_s_setprio(0);
  }
#undef STAGEKV
#undef LDSOFF

  // epilogue: l is per-q (q=n16), spread over quads -> reduce over quads,
  // then each lane fetches l for its output rows q=quad*4+r via shfl.
  {
    float s = l;
    s += __shfl_xor(s, 16);
    s += __shfl_xor(s, 32);
    for (int nd = 0; nd < 4; nd++)
      for (int r = 0; r < 4; r++) {
        float linv = 1.0f / __shfl(s, quad * 4 + r);
        int q = q0 + quad * 4 + r;
        int ch = h * 64 + nd * 16 + n16;
        attnT[((size_t)b * 1024 + q) * 512 + ch] = f2bs(O[nd][r] * linv);
      }
  }
}

// ---------------------------------------------------------------------------
// Kernel 4: projection GEMM + bias + residual, 64x64 tiles (r7, kept).
// ---------------------------------------------------------------------------
__global__ __launch_bounds__(256) void gemm_out(
    const short* __restrict__ Wb, const short* __restrict__ Xt,
    const float* __restrict__ bias, const float* __restrict__ resid,
    float* __restrict__ out) {
  __shared__ short As[2][2048];   // 64 rows x 32 k
  __shared__ short Bs[2][2048];
  int bx = blockIdx.x, by = blockIdx.y, bb = blockIdx.z;
  int m0 = by * 64, n0 = bx * 64;
  int t = threadIdx.x;
  int w = t >> 6, lane = t & 63, n16 = lane & 15, quad = lane >> 4;
  int wm = (w >> 1) * 32, wn = (w & 1) * 32;

  const short* Wa = Wb + (size_t)(m0 + (t >> 2)) * 512 + (t & 3) * 8;
  const short* Xa = Xt + (size_t)bb * 1024 * 512 +
                    (size_t)(n0 + (t >> 2)) * 512 + (t & 3) * 8;

#define STAGE(buf, kk)                                                \
  do {                                                                \
    glds16(Wa + (kk), &As[buf][t * 8]);                               \
    glds16(Xa + (kk), &Bs[buf][t * 8]);                               \
  } while (0)

  floatx4 acc[2][2];
  for (int i = 0; i < 2; i++)
    for (int j = 0; j < 2; j++) acc[i][j] = (floatx4){0.f, 0.f, 0.f, 0.f};

  STAGE(0, 0);
#pragma unroll 1
  for (int ks = 0; ks < 16; ks++) {
    int cur = ks & 1;
    __syncthreads();
    if (ks < 15) STAGE(cur ^ 1, (ks + 1) * 32);
    short8 a[2], b[2];
    for (int im = 0; im < 2; im++)
      a[im] = *reinterpret_cast<const short8*>(
          &As[cur][(wm + im * 16 + n16) * 32 + quad * 8]);
    for (int in = 0; in < 2; in++)
      b[in] = *reinterpret_cast<const short8*>(
          &Bs[cur][(wn + in * 16 + n16) * 32 + quad * 8]);
    for (int im = 0; im < 2; im++)
      for (int in = 0; in < 2; in++)
        acc[im][in] = MFMA(a[im], b[in], acc[im][in]);
  }
#undef STAGE

  for (int im = 0; im < 2; im++) {
    int m = m0 + wm + im * 16 + quad * 4;
    float4 bi = *reinterpret_cast<const float4*>(&bias[m]);
    for (int in = 0; in < 2; in++) {
      int nn = n0 + wn + in * 16 + n16;
      size_t idx = ((size_t)bb * 512 + m) * 1024 + nn;
      out[idx]        = acc[im][in][0] + bi.x + resid[idx];
      out[idx + 1024] = acc[im][in][1] + bi.y + resid[idx + 1024];
      out[idx + 2048] = acc[im][in][2] + bi.z + resid[idx + 2048];
      out[idx + 3072] = acc[im][in][3] + bi.w + resid[idx + 3072];
    }
  }
}

// ---------------------------------------------------------------------------
extern "C" void kernel_launch(void* const* d_in, const int* in_sizes, int n_in,
                              void* d_out, int out_size, void* d_ws, size_t ws_size,
                              hipStream_t stream) {
  const float* x     = (const float*)d_in[0];
  const float* gamma = (const float*)d_in[1];
  const float* beta  = (const float*)d_in[2];
  const float* w_in  = (const float*)d_in[3];
  const float* b_in  = (const float*)d_in[4];
  const float* w_out = (const float*)d_in[5];
  const float* b_out = (const float*)d_in[6];
  float* out = (float*)d_out;

  char* ws = (char*)d_ws;
  short* ht    = (short*)ws;                    //  8 MiB [8][1024][512]
  short* Qt    = (short*)(ws + (8u  << 20));    //  8 MiB [64][1024][64]
  short* Kt    = (short*)(ws + (16u << 20));    //  8 MiB [64][1024][64]
  short* Vn    = (short*)(ws + (24u << 20));    //  8 MiB [8][512][1024]
  short* attnT = (short*)(ws + (32u << 20));    //  8 MiB [8][1024][512]
  short* wbf1  = (short*)(ws + (40u << 20));    //  1.5 MiB
  short* wbf2  = (short*)(ws + (42u << 20));    //  0.5 MiB

  gn_cast_fused<<<1280, 256, 0, stream>>>(x, gamma, beta, ht,
                                          w_in, wbf1, w_out, wbf2);
  gemm_qkv<<<dim3(8, 12, B_), 256, 0, stream>>>(wbf1, ht, b_in, Qt, Kt, Vn);
  attn_mfma<<<1024, 256, 0, stream>>>(Qt, Kt, Vn, attnT);
  gemm_out<<<dim3(16, 8, B_), 256, 0, stream>>>(wbf2, attnT, b_out, x, out);
}

// Round 16
// 158.643 us; speedup vs baseline: 1.1967x; 1.0056x over previous
//
#include <hip/hip_runtime.h>
#include <hip/hip_bf16.h>

// Problem dims (fixed by reference)
#define B_    8
#define C_    512
#define HW_   1024     // H*W = 32*32
#define NG    32
#define GCH   16
#define EPSV  1e-6f

typedef __attribute__((ext_vector_type(8))) short short8;   // 8 bf16 (4 VGPRs)
typedef __attribute__((ext_vector_type(4))) short short4v;  // 4 bf16
typedef __attribute__((ext_vector_type(4))) float floatx4;  // MFMA C/D

static __device__ __forceinline__ short f2bs(float f) {
  return __builtin_bit_cast(short, __float2bfloat16(f));
}
static __device__ __forceinline__ short4v pack4(float a, float b, float c, float d) {
  return (short4v){f2bs(a), f2bs(b), f2bs(c), f2bs(d)};
}
static __device__ __forceinline__ unsigned pk2(float a, float b) {
  return (unsigned)(unsigned short)f2bs(a) |
         ((unsigned)(unsigned short)f2bs(b) << 16);
}
#define MFMA(a, b, c) __builtin_amdgcn_mfma_f32_16x16x32_bf16((a), (b), (c), 0, 0, 0)

// async global->LDS, 16 B per lane (global_load_lds_dwordx4)
static __device__ __forceinline__ void glds16(const short* g, short* l) {
  __builtin_amdgcn_global_load_lds(
      (const __attribute__((address_space(1))) void*)g,
      (__attribute__((address_space(3))) void*)l, 16, 0, 0);
}

// ---------------------------------------------------------------------------
// Kernel 1 (fused): GroupNorm stats+apply+transpose AND both weight casts.
//   r16: phase 1 reads x in the phase-2 access pattern (row r=t>>4, 16
//   chunks along HW -- 256B coalesced segments) and keeps all 16 float4 in
//   REGISTERS (statically indexed, full unroll).  Phase 2 never re-reads x:
//   deletes 64 MB of L2 reads + 16 load issues per thread.
// ---------------------------------------------------------------------------
__global__ __launch_bounds__(256) void gn_cast_fused(
    const float* __restrict__ x, const float* __restrict__ gamma,
    const float* __restrict__ beta, short* __restrict__ ht,
    const float* __restrict__ w_in, short* __restrict__ wbf1,
    const float* __restrict__ w_out, short* __restrict__ wbf2) {
  int blk = blockIdx.x;
  int t = threadIdx.x;

  if (blk >= 256) {                      // ---- weight cast blocks ----
    int i = (blk - 256) * 256 + t;       // 262144 float4s total
    const float* s; short* d; int j;
    if (i < 196608) { s = w_in; d = wbf1; j = i; }
    else            { s = w_out; d = wbf2; j = i - 196608; }
    float4 v = reinterpret_cast<const float4*>(s)[j];
    reinterpret_cast<short4v*>(d)[j] = pack4(v.x, v.y, v.z, v.w);
    return;
  }

  // ---- GroupNorm block: (b, g) ----
  int b = blk >> 5, g = blk & 31;
  const float* xp = x + ((size_t)(b * C_) + g * GCH) * HW_;  // 16 ch x 1024

  __shared__ float Ls[4 * 1040];         // 4 subtiles of [16][65]  16.6 KB
  __shared__ float rs_[4], rss_[4], st_[2];

  int r = t >> 4, c4 = t & 15;

  // phase 1: load in phase-2 layout, keep in registers, accumulate stats
  float4 vals[16];
  float s = 0.f, ss = 0.f;
#pragma unroll
  for (int i = 0; i < 16; i++) {
    float4 v = *reinterpret_cast<const float4*>(
        xp + (size_t)r * HW_ + i * 64 + c4 * 4);
    vals[i] = v;
    s  += (v.x + v.y) + (v.z + v.w);
    ss += (v.x * v.x + v.y * v.y) + (v.z * v.z + v.w * v.w);
  }
  for (int o = 32; o > 0; o >>= 1) {
    s  += __shfl_down(s, o);
    ss += __shfl_down(ss, o);
  }
  int wid = t >> 6, lane = t & 63;
  if (lane == 0) { rs_[wid] = s; rss_[wid] = ss; }
  __syncthreads();
  if (t == 0) {
    float stot  = rs_[0] + rs_[1] + rs_[2] + rs_[3];
    float sstot = rss_[0] + rss_[1] + rss_[2] + rss_[3];
    float mean = stot / 16384.f;
    float var  = sstot / 16384.f - mean * mean;
    st_[0] = mean;
    st_[1] = rsqrtf(var + EPSV);
  }
  __syncthreads();

  int ch = g * GCH + r;
  float ga = gamma[ch] * st_[1];
  float be = beta[ch] - st_[0] * ga;
  int sq = t >> 2, cq = t & 3;

  // phase 2: normalize from registers, transpose via LDS, write ht
#pragma unroll
  for (int it = 0; it < 4; it++) {
#pragma unroll
    for (int sub = 0; sub < 4; sub++) {
      float4 v = vals[it * 4 + sub];
      float* L = Ls + sub * 1040;
      L[r * 65 + c4 * 4 + 0] = v.x * ga + be;
      L[r * 65 + c4 * 4 + 1] = v.y * ga + be;
      L[r * 65 + c4 * 4 + 2] = v.z * ga + be;
      L[r * 65 + c4 * 4 + 3] = v.w * ga + be;
    }
    __syncthreads();
#pragma unroll
    for (int sub = 0; sub < 4; sub++) {
      int s0 = (it * 4 + sub) * 64;
      const float* L = Ls + sub * 1040;
      float a0 = L[(cq * 4 + 0) * 65 + sq];
      float a1 = L[(cq * 4 + 1) * 65 + sq];
      float a2 = L[(cq * 4 + 2) * 65 + sq];
      float a3 = L[(cq * 4 + 3) * 65 + sq];
      *reinterpret_cast<short4v*>(
          ht + ((size_t)b * 1024 + s0 + sq) * 512 + g * GCH + cq * 4) =
          pack4(a0, a1, a2, a3);
    }
    __syncthreads();
  }
}

// ---------------------------------------------------------------------------
// Kernel 2: QKV GEMM, m97 structure + XCD swizzle (r16).
//   768 blocks = 8 batches x 96.  batch k -> XCD k: per-XCD L2 working set
//   = ht panel (1 MB) + W (1.5 MB) < 4 MB, so B-panel reads become L2 hits
//   (previously every XCD mixed all 8 batches' panels: 8 MB > 4 MB).
// ---------------------------------------------------------------------------
__global__ __launch_bounds__(256) void gemm_qkv(
    const short* __restrict__ Wb, const short* __restrict__ ht,
    const float* __restrict__ bias,
    short* __restrict__ Qt, short* __restrict__ Kt, short* __restrict__ Vn) {
  __shared__ short As[2][4096];   // [buf][row*32 + k]  128 rows x 32 k
  __shared__ short Bs[2][4096];
  int blk0 = blockIdx.x;
  int blk = (blk0 & 7) * 96 + (blk0 >> 3);   // 768 = 8 XCD x 96: batch->XCD
  int bb = blk / 96;
  int rem = blk % 96;
  int by = rem >> 3, bx = rem & 7;
  int m0 = by * 128, n0 = bx * 128;
  int t = threadIdx.x;
  int w = t >> 6, lane = t & 63, n16 = lane & 15, quad = lane >> 4;
  int wm = (w >> 1) * 64, wn = (w & 1) * 64;

  const short* Wa = Wb + (size_t)(m0 + (t >> 2)) * 512 + (t & 3) * 8;
  const short* Xa = ht + (size_t)bb * 1024 * 512 +
                    (size_t)(n0 + (t >> 2)) * 512 + (t & 3) * 8;

#define STAGE(buf, kk)                                                \
  do {                                                                \
    glds16(Wa + (kk), &As[buf][t * 8]);                               \
    glds16(Wa + 64 * 512 + (kk), &As[buf][2048 + t * 8]);             \
    glds16(Xa + (kk), &Bs[buf][t * 8]);                               \
    glds16(Xa + 64 * 512 + (kk), &Bs[buf][2048 + t * 8]);             \
  } while (0)

  floatx4 acc[4][4];
  for (int i = 0; i < 4; i++)
    for (int j = 0; j < 4; j++) acc[i][j] = (floatx4){0.f, 0.f, 0.f, 0.f};

  STAGE(0, 0);
#pragma unroll 1
  for (int ks = 0; ks < 16; ks++) {
    int cur = ks & 1;
    __syncthreads();                       // drains staging + prior ds_reads
    if (ks < 15) STAGE(cur ^ 1, (ks + 1) * 32);
    short8 a[4], b[4];
    for (int im = 0; im < 4; im++)
      a[im] = *reinterpret_cast<const short8*>(
          &As[cur][(wm + im * 16 + n16) * 32 + quad * 8]);
    for (int in = 0; in < 4; in++)
      b[in] = *reinterpret_cast<const short8*>(
          &Bs[cur][(wn + in * 16 + n16) * 32 + quad * 8]);
    for (int im = 0; im < 4; im++)
      for (int in = 0; in < 4; in++)
        acc[im][in] = MFMA(a[im], b[in], acc[im][in]);
  }
#undef STAGE

  if (m0 < 1024) {                 // Q or K: transposed store [seq][d]
    const bool isQ = (m0 < 512);
    short* base = isQ ? Qt : Kt;
    const float sc = isQ ? 0.125f : 1.0f;   // fold 1/sqrt(64) into Q
    for (int im = 0; im < 4; im++) {
      int m = m0 + wm + im * 16 + quad * 4;
      int hh = (m >> 6) & 7, d0 = m & 63;
      float4 bi = *reinterpret_cast<const float4*>(&bias[m]);
      short* hb = base + (size_t)(bb * 8 + hh) * 1024 * 64 + d0;
      for (int in = 0; in < 4; in++) {
        int nn = n0 + wn + in * 16 + n16;
        *reinterpret_cast<short4v*>(hb + (size_t)nn * 64) =
            pack4((acc[im][in][0] + bi.x) * sc, (acc[im][in][1] + bi.y) * sc,
                  (acc[im][in][2] + bi.z) * sc, (acc[im][in][3] + bi.w) * sc);
      }
    }
  } else {                         // V: natural store [ch][seq]
    for (int im = 0; im < 4; im++) {
      int m = m0 + wm + im * 16 + quad * 4;
      float4 bi = *reinterpret_cast<const float4*>(&bias[m]);
      int ch = m - 1024;
      for (int in = 0; in < 4; in++) {
        int nn = n0 + wn + in * 16 + n16;
        short* vp = Vn + (size_t)(bb * 512 + ch) * 1024 + nn;
        vp[0]    = f2bs(acc[im][in][0] + bi.x);
        vp[1024] = f2bs(acc[im][in][1] + bi.y);
        vp[2048] = f2bs(acc[im][in][2] + bi.z);
        vp[3072] = f2bs(acc[im][in][3] + bi.w);
      }
    }
  }
}

// ---------------------------------------------------------------------------
// Kernel 3: attention -- EXACT r15 body (best known: LDS-staged K/V via
// VGPR-free glds, swapped-QK in-register softmax, 1024 blocks = 4/CU).
// ---------------------------------------------------------------------------
__global__ __launch_bounds__(256) void attn_mfma(
    const short* __restrict__ Qt, const short* __restrict__ Kt,
    const short* __restrict__ Vn, short* __restrict__ attnT) {
  __shared__ short KT[2][4096];   // [buf][64 rows][64 d]  8 KB per buf
  __shared__ short VT[2][4096];   // [buf][64 ch][64 kv]
  int blk0 = blockIdx.x;
  int blk = (blk0 & 7) * 128 + (blk0 >> 3);  // 1024 = 8 XCD x 128: batch->XCD
  int qb = blk & 15, h = (blk >> 4) & 7, b = blk >> 7;
  int t = threadIdx.x;
  int w = t >> 6, lane = t & 63, n16 = lane & 15, quad = lane >> 4;
  int q0 = qb * 64 + w * 16;
  int qhi = quad >> 1;
  int srcA = ((quad & 1) << 5) + n16;
  int srcB = srcA + 16;

  const short* Qp = Qt + (size_t)(b * 8 + h) * 1024 * 64;
  const short* Kp = Kt + (size_t)(b * 8 + h) * 1024 * 64;
  const short* Vp = Vn + (size_t)(b * 512 + h * 64) * 1024;

  short8 qa[2];
  for (int f = 0; f < 2; f++)
    qa[f] = *reinterpret_cast<const short8*>(
        Qp + (size_t)(q0 + n16) * 64 + f * 32 + quad * 8);

  floatx4 O[4];
  float l = 0.f;
  for (int i = 0; i < 4; i++) O[i] = (floatx4){0.f, 0.f, 0.f, 0.f};

  // staging chunk geometry (per thread: 2 chunks of 16 B per tile)
  int p0 = t * 16, p1 = 4096 + t * 16;           // LDS byte offsets
  int r0 = p0 >> 7, c0 = (p0 & 127) ^ ((r0 & 7) << 4);
  int r1 = p1 >> 7, c1 = (p1 & 127) ^ ((r1 & 7) << 4);

#define STAGEKV(buf, ktv)                                                    \
  do {                                                                       \
    const char* Kb_ = (const char*)Kp + (ktv) * 8192;                        \
    const char* Vb_ = (const char*)Vp + (ktv) * 128;                         \
    glds16((const short*)(Kb_ + r0 * 128 + c0), &KT[buf][p0 >> 1]);          \
    glds16((const short*)(Kb_ + r1 * 128 + c1), &KT[buf][p1 >> 1]);          \
    glds16((const short*)(Vb_ + (size_t)r0 * 2048 + c0), &VT[buf][p0 >> 1]); \
    glds16((const short*)(Vb_ + (size_t)r1 * 2048 + c1), &VT[buf][p1 >> 1]); \
  } while (0)

// swizzled LDS byte offset for a 16B read at (row, colbyte)
#define LDSOFF(row, colb) ((row) * 128 + (((colb) ^ (((row) & 7) << 4))))

  STAGEKV(0, 0);
#pragma unroll 1
  for (int kt = 0; kt < 16; kt++) {
    int cur = kt & 1;
    __syncthreads();                       // drains staging + prior ds_reads
    if (kt < 15) STAGEKV(cur ^ 1, kt + 1);

    short8 kf[4][2], v[4][2];
#pragma unroll
    for (int nt = 0; nt < 4; nt++)
#pragma unroll
      for (int f = 0; f < 2; f++) {
        kf[nt][f] = *reinterpret_cast<const short8*>(
            (const char*)&KT[cur][0] +
            LDSOFF(nt * 16 + n16, f * 64 + quad * 16));
        v[nt][f] = *reinterpret_cast<const short8*>(
            (const char*)&VT[cur][0] +
            LDSOFF(nt * 16 + n16, f * 64 + quad * 16));
      }

    floatx4 T[4];
#pragma unroll
    for (int nt = 0; nt < 4; nt++) {
      floatx4 s_ = (floatx4){0.f, 0.f, 0.f, 0.f};
      s_ = MFMA(kf[nt][0], qa[0], s_);
      T[nt] = MFMA(kf[nt][1], qa[1], s_);
    }
    unsigned u[4][2];
#pragma unroll
    for (int nt = 0; nt < 4; nt++) {
      float p0_ = __expf(T[nt][0]);
      float p1_ = __expf(T[nt][1]);
      float p2_ = __expf(T[nt][2]);
      float p3_ = __expf(T[nt][3]);
      l += (p0_ + p1_) + (p2_ + p3_);
      u[nt][0] = pk2(p0_, p1_);
      u[nt][1] = pk2(p2_, p3_);
    }
    short8 pa[2];
#pragma unroll
    for (int f = 0; f < 2; f++) {
      unsigned a0 = (unsigned)__shfl((int)u[2 * f + 0][0], srcA);
      unsigned a1 = (unsigned)__shfl((int)u[2 * f + 1][0], srcA);
      unsigned b0 = (unsigned)__shfl((int)u[2 * f + 0][1], srcA);
      unsigned b1 = (unsigned)__shfl((int)u[2 * f + 1][1], srcA);
      unsigned c0_ = (unsigned)__shfl((int)u[2 * f + 0][0], srcB);
      unsigned c1_ = (unsigned)__shfl((int)u[2 * f + 1][0], srcB);
      unsigned d0 = (unsigned)__shfl((int)u[2 * f + 0][1], srcB);
      unsigned d1 = (unsigned)__shfl((int)u[2 * f + 1][1], srcB);
      uint4 wv;
      wv.x = qhi ? a1 : a0;
      wv.y = qhi ? b1 : b0;
      wv.z = qhi ? c1_ : c0_;
      wv.w = qhi ? d1 : d0;
      pa[f] = __builtin_bit_cast(short8, wv);
    }
    __builtin_amdgcn_s_setprio(1);
#pragma unroll
    for (int nd = 0; nd < 4; nd++) {
      O[nd] = MFMA(pa[0], v[nd][0], O[nd]);
      O[nd] = MFMA(pa[1], v[nd][1], O[nd]);
    }
    __builtin_amdgcn_s_setprio(0);
  }
#undef STAGEKV
#undef LDSOFF

  // epilogue: l is per-q (q=n16), spread over quads -> reduce over quads,
  // then each lane fetches l for its output rows q=quad*4+r via shfl.
  {
    float s = l;
    s += __shfl_xor(s, 16);
    s += __shfl_xor(s, 32);
    for (int nd = 0; nd < 4; nd++)
      for (int r = 0; r < 4; r++) {
        float linv = 1.0f / __shfl(s, quad * 4 + r);
        int q = q0 + quad * 4 + r;
        int ch = h * 64 + nd * 16 + n16;
        attnT[((size_t)b * 1024 + q) * 512 + ch] = f2bs(O[nd][r] * linv);
      }
  }
}

// ---------------------------------------------------------------------------
// Kernel 4: projection GEMM + bias + residual, 64x64 tiles + XCD swizzle
//   (r16): 1024 blocks = 8 batches x 128; batch k -> XCD k keeps the
//   attnT panel (1 MB) L2-resident across its 8 m-blocks.
// ---------------------------------------------------------------------------
__global__ __launch_bounds__(256) void gemm_out(
    const short* __restrict__ Wb, const short* __restrict__ Xt,
    const float* __restrict__ bias, const float* __restrict__ resid,
    float* __restrict__ out) {
  __shared__ short As[2][2048];   // 64 rows x 32 k
  __shared__ short Bs[2][2048];
  int blk0 = blockIdx.x;
  int blk = (blk0 & 7) * 128 + (blk0 >> 3);  // 1024 = 8 XCD x 128: batch->XCD
  int bb = blk >> 7;
  int rem = blk & 127;
  int by = rem >> 4, bx = rem & 15;
  int m0 = by * 64, n0 = bx * 64;
  int t = threadIdx.x;
  int w = t >> 6, lane = t & 63, n16 = lane & 15, quad = lane >> 4;
  int wm = (w >> 1) * 32, wn = (w & 1) * 32;

  const short* Wa = Wb + (size_t)(m0 + (t >> 2)) * 512 + (t & 3) * 8;
  const short* Xa = Xt + (size_t)bb * 1024 * 512 +
                    (size_t)(n0 + (t >> 2)) * 512 + (t & 3) * 8;

#define STAGE(buf, kk)                                                \
  do {                                                                \
    glds16(Wa + (kk), &As[buf][t * 8]);                               \
    glds16(Xa + (kk), &Bs[buf][t * 8]);                               \
  } while (0)

  floatx4 acc[2][2];
  for (int i = 0; i < 2; i++)
    for (int j = 0; j < 2; j++) acc[i][j] = (floatx4){0.f, 0.f, 0.f, 0.f};

  STAGE(0, 0);
#pragma unroll 1
  for (int ks = 0; ks < 16; ks++) {
    int cur = ks & 1;
    __syncthreads();
    if (ks < 15) STAGE(cur ^ 1, (ks + 1) * 32);
    short8 a[2], b[2];
    for (int im = 0; im < 2; im++)
      a[im] = *reinterpret_cast<const short8*>(
          &As[cur][(wm + im * 16 + n16) * 32 + quad * 8]);
    for (int in = 0; in < 2; in++)
      b[in] = *reinterpret_cast<const short8*>(
          &Bs[cur][(wn + in * 16 + n16) * 32 + quad * 8]);
    for (int im = 0; im < 2; im++)
      for (int in = 0; in < 2; in++)
        acc[im][in] = MFMA(a[im], b[in], acc[im][in]);
  }
#undef STAGE

  for (int im = 0; im < 2; im++) {
    int m = m0 + wm + im * 16 + quad * 4;
    float4 bi = *reinterpret_cast<const float4*>(&bias[m]);
    for (int in = 0; in < 2; in++) {
      int nn = n0 + wn + in * 16 + n16;
      size_t idx = ((size_t)bb * 512 + m) * 1024 + nn;
      out[idx]        = acc[im][in][0] + bi.x + resid[idx];
      out[idx + 1024] = acc[im][in][1] + bi.y + resid[idx + 1024];
      out[idx + 2048] = acc[im][in][2] + bi.z + resid[idx + 2048];
      out[idx + 3072] = acc[im][in][3] + bi.w + resid[idx + 3072];
    }
  }
}

// ---------------------------------------------------------------------------
extern "C" void kernel_launch(void* const* d_in, const int* in_sizes, int n_in,
                              void* d_out, int out_size, void* d_ws, size_t ws_size,
                              hipStream_t stream) {
  const float* x     = (const float*)d_in[0];
  const float* gamma = (const float*)d_in[1];
  const float* beta  = (const float*)d_in[2];
  const float* w_in  = (const float*)d_in[3];
  const float* b_in  = (const float*)d_in[4];
  const float* w_out = (const float*)d_in[5];
  const float* b_out = (const float*)d_in[6];
  float* out = (float*)d_out;

  char* ws = (char*)d_ws;
  short* ht    = (short*)ws;                    //  8 MiB [8][1024][512]
  short* Qt    = (short*)(ws + (8u  << 20));    //  8 MiB [64][1024][64]
  short* Kt    = (short*)(ws + (16u << 20));    //  8 MiB [64][1024][64]
  short* Vn    = (short*)(ws + (24u << 20));    //  8 MiB [8][512][1024]
  short* attnT = (short*)(ws + (32u << 20));    //  8 MiB [8][1024][512]
  short* wbf1  = (short*)(ws + (40u << 20));    //  1.5 MiB
  short* wbf2  = (short*)(ws + (42u << 20));    //  0.5 MiB

  gn_cast_fused<<<1280, 256, 0, stream>>>(x, gamma, beta, ht,
                                          w_in, wbf1, w_out, wbf2);
  gemm_qkv<<<768, 256, 0, stream>>>(wbf1, ht, b_in, Qt, Kt, Vn);
  attn_mfma<<<1024, 256, 0, stream>>>(Qt, Kt, Vn, attnT);
  gemm_out<<<1024, 256, 0, stream>>>(wbf2, attnT, b_out, x, out);
}

// Round 17
// 157.767 us; speedup vs baseline: 1.2034x; 1.0056x over previous
//
#include <hip/hip_runtime.h>
#include <hip/hip_bf16.h>

// Problem dims (fixed by reference)
#define B_    8
#define C_    512
#define HW_   1024     // H*W = 32*32
#define NG    32
#define GCH   16
#define EPSV  1e-6f

typedef __attribute__((ext_vector_type(8))) short short8;   // 8 bf16 (4 VGPRs)
typedef __attribute__((ext_vector_type(4))) short short4v;  // 4 bf16
typedef __attribute__((ext_vector_type(4))) float floatx4;  // MFMA C/D

static __device__ __forceinline__ short f2bs(float f) {
  return __builtin_bit_cast(short, __float2bfloat16(f));
}
static __device__ __forceinline__ short4v pack4(float a, float b, float c, float d) {
  return (short4v){f2bs(a), f2bs(b), f2bs(c), f2bs(d)};
}
static __device__ __forceinline__ unsigned pk2(float a, float b) {
  return (unsigned)(unsigned short)f2bs(a) |
         ((unsigned)(unsigned short)f2bs(b) << 16);
}
#define MFMA(a, b, c) __builtin_amdgcn_mfma_f32_16x16x32_bf16((a), (b), (c), 0, 0, 0)

// async global->LDS, 16 B per lane (global_load_lds_dwordx4)
static __device__ __forceinline__ void glds16(const short* g, short* l) {
  __builtin_amdgcn_global_load_lds(
      (const __attribute__((address_space(1))) void*)g,
      (__attribute__((address_space(3))) void*)l, 16, 0, 0);
}

// ---------------------------------------------------------------------------
// Kernel 1 (fused): GroupNorm stats+apply+transpose AND both weight casts.
// (unchanged from r16 -- register-resident phase 2, x read once)
// ---------------------------------------------------------------------------
__global__ __launch_bounds__(256) void gn_cast_fused(
    const float* __restrict__ x, const float* __restrict__ gamma,
    const float* __restrict__ beta, short* __restrict__ ht,
    const float* __restrict__ w_in, short* __restrict__ wbf1,
    const float* __restrict__ w_out, short* __restrict__ wbf2) {
  int blk = blockIdx.x;
  int t = threadIdx.x;

  if (blk >= 256) {                      // ---- weight cast blocks ----
    int i = (blk - 256) * 256 + t;       // 262144 float4s total
    const float* s; short* d; int j;
    if (i < 196608) { s = w_in; d = wbf1; j = i; }
    else            { s = w_out; d = wbf2; j = i - 196608; }
    float4 v = reinterpret_cast<const float4*>(s)[j];
    reinterpret_cast<short4v*>(d)[j] = pack4(v.x, v.y, v.z, v.w);
    return;
  }

  // ---- GroupNorm block: (b, g) ----
  int b = blk >> 5, g = blk & 31;
  const float* xp = x + ((size_t)(b * C_) + g * GCH) * HW_;  // 16 ch x 1024

  __shared__ float Ls[4 * 1040];         // 4 subtiles of [16][65]  16.6 KB
  __shared__ float rs_[4], rss_[4], st_[2];

  int r = t >> 4, c4 = t & 15;

  // phase 1: load in phase-2 layout, keep in registers, accumulate stats
  float4 vals[16];
  float s = 0.f, ss = 0.f;
#pragma unroll
  for (int i = 0; i < 16; i++) {
    float4 v = *reinterpret_cast<const float4*>(
        xp + (size_t)r * HW_ + i * 64 + c4 * 4);
    vals[i] = v;
    s  += (v.x + v.y) + (v.z + v.w);
    ss += (v.x * v.x + v.y * v.y) + (v.z * v.z + v.w * v.w);
  }
  for (int o = 32; o > 0; o >>= 1) {
    s  += __shfl_down(s, o);
    ss += __shfl_down(ss, o);
  }
  int wid = t >> 6, lane = t & 63;
  if (lane == 0) { rs_[wid] = s; rss_[wid] = ss; }
  __syncthreads();
  if (t == 0) {
    float stot  = rs_[0] + rs_[1] + rs_[2] + rs_[3];
    float sstot = rss_[0] + rss_[1] + rss_[2] + rss_[3];
    float mean = stot / 16384.f;
    float var  = sstot / 16384.f - mean * mean;
    st_[0] = mean;
    st_[1] = rsqrtf(var + EPSV);
  }
  __syncthreads();

  int ch = g * GCH + r;
  float ga = gamma[ch] * st_[1];
  float be = beta[ch] - st_[0] * ga;
  int sq = t >> 2, cq = t & 3;

  // phase 2: normalize from registers, transpose via LDS, write ht
#pragma unroll
  for (int it = 0; it < 4; it++) {
#pragma unroll
    for (int sub = 0; sub < 4; sub++) {
      float4 v = vals[it * 4 + sub];
      float* L = Ls + sub * 1040;
      L[r * 65 + c4 * 4 + 0] = v.x * ga + be;
      L[r * 65 + c4 * 4 + 1] = v.y * ga + be;
      L[r * 65 + c4 * 4 + 2] = v.z * ga + be;
      L[r * 65 + c4 * 4 + 3] = v.w * ga + be;
    }
    __syncthreads();
#pragma unroll
    for (int sub = 0; sub < 4; sub++) {
      int s0 = (it * 4 + sub) * 64;
      const float* L = Ls + sub * 1040;
      float a0 = L[(cq * 4 + 0) * 65 + sq];
      float a1 = L[(cq * 4 + 1) * 65 + sq];
      float a2 = L[(cq * 4 + 2) * 65 + sq];
      float a3 = L[(cq * 4 + 3) * 65 + sq];
      *reinterpret_cast<short4v*>(
          ht + ((size_t)b * 1024 + s0 + sq) * 512 + g * GCH + cq * 4) =
          pack4(a0, a1, a2, a3);
    }
    __syncthreads();
  }
}

// ---------------------------------------------------------------------------
// Kernel 2: QKV GEMM, m97 structure + XCD swizzle (unchanged from r16).
// ---------------------------------------------------------------------------
__global__ __launch_bounds__(256) void gemm_qkv(
    const short* __restrict__ Wb, const short* __restrict__ ht,
    const float* __restrict__ bias,
    short* __restrict__ Qt, short* __restrict__ Kt, short* __restrict__ Vn) {
  __shared__ short As[2][4096];   // [buf][row*32 + k]  128 rows x 32 k
  __shared__ short Bs[2][4096];
  int blk0 = blockIdx.x;
  int blk = (blk0 & 7) * 96 + (blk0 >> 3);   // 768 = 8 XCD x 96: batch->XCD
  int bb = blk / 96;
  int rem = blk % 96;
  int by = rem >> 3, bx = rem & 7;
  int m0 = by * 128, n0 = bx * 128;
  int t = threadIdx.x;
  int w = t >> 6, lane = t & 63, n16 = lane & 15, quad = lane >> 4;
  int wm = (w >> 1) * 64, wn = (w & 1) * 64;

  const short* Wa = Wb + (size_t)(m0 + (t >> 2)) * 512 + (t & 3) * 8;
  const short* Xa = ht + (size_t)bb * 1024 * 512 +
                    (size_t)(n0 + (t >> 2)) * 512 + (t & 3) * 8;

#define STAGE(buf, kk)                                                \
  do {                                                                \
    glds16(Wa + (kk), &As[buf][t * 8]);                               \
    glds16(Wa + 64 * 512 + (kk), &As[buf][2048 + t * 8]);             \
    glds16(Xa + (kk), &Bs[buf][t * 8]);                               \
    glds16(Xa + 64 * 512 + (kk), &Bs[buf][2048 + t * 8]);             \
  } while (0)

  floatx4 acc[4][4];
  for (int i = 0; i < 4; i++)
    for (int j = 0; j < 4; j++) acc[i][j] = (floatx4){0.f, 0.f, 0.f, 0.f};

  STAGE(0, 0);
#pragma unroll 1
  for (int ks = 0; ks < 16; ks++) {
    int cur = ks & 1;
    __syncthreads();                       // drains staging + prior ds_reads
    if (ks < 15) STAGE(cur ^ 1, (ks + 1) * 32);
    short8 a[4], b[4];
    for (int im = 0; im < 4; im++)
      a[im] = *reinterpret_cast<const short8*>(
          &As[cur][(wm + im * 16 + n16) * 32 + quad * 8]);
    for (int in = 0; in < 4; in++)
      b[in] = *reinterpret_cast<const short8*>(
          &Bs[cur][(wn + in * 16 + n16) * 32 + quad * 8]);
    for (int im = 0; im < 4; im++)
      for (int in = 0; in < 4; in++)
        acc[im][in] = MFMA(a[im], b[in], acc[im][in]);
  }
#undef STAGE

  if (m0 < 1024) {                 // Q or K: transposed store [seq][d]
    const bool isQ = (m0 < 512);
    short* base = isQ ? Qt : Kt;
    const float sc = isQ ? 0.125f : 1.0f;   // fold 1/sqrt(64) into Q
    for (int im = 0; im < 4; im++) {
      int m = m0 + wm + im * 16 + quad * 4;
      int hh = (m >> 6) & 7, d0 = m & 63;
      float4 bi = *reinterpret_cast<const float4*>(&bias[m]);
      short* hb = base + (size_t)(bb * 8 + hh) * 1024 * 64 + d0;
      for (int in = 0; in < 4; in++) {
        int nn = n0 + wn + in * 16 + n16;
        *reinterpret_cast<short4v*>(hb + (size_t)nn * 64) =
            pack4((acc[im][in][0] + bi.x) * sc, (acc[im][in][1] + bi.y) * sc,
                  (acc[im][in][2] + bi.z) * sc, (acc[im][in][3] + bi.w) * sc);
      }
    }
  } else {                         // V: natural store [ch][seq]
    for (int im = 0; im < 4; im++) {
      int m = m0 + wm + im * 16 + quad * 4;
      float4 bi = *reinterpret_cast<const float4*>(&bias[m]);
      int ch = m - 1024;
      for (int in = 0; in < 4; in++) {
        int nn = n0 + wn + in * 16 + n16;
        short* vp = Vn + (size_t)(bb * 512 + ch) * 1024 + nn;
        vp[0]    = f2bs(acc[im][in][0] + bi.x);
        vp[1024] = f2bs(acc[im][in][1] + bi.y);
        vp[2048] = f2bs(acc[im][in][2] + bi.z);
        vp[3072] = f2bs(acc[im][in][3] + bi.w);
      }
    }
  }
}

// ---------------------------------------------------------------------------
// Kernel 3: attention -- r15/r16 body + coalesced epilogue (r17).
//   Epilogue was 16 scalar 2B global stores per lane (G13 violation).
//   After the kt loop KT[0] is free (kt=15 reads only KT[1]; the kt=15
//   barrier put every wave past kt=14): each wave dumps its normalized
//   16x64 bf16 tile into a private 2KB scratch slice (ds_write_b16,
//   <=2-way conflict = free), then stores attnT as 2x16B coalesced
//   chunks per lane (128B-contiguous rows).  No new barriers.
// ---------------------------------------------------------------------------
__global__ __launch_bounds__(256) void attn_mfma(
    const short* __restrict__ Qt, const short* __restrict__ Kt,
    const short* __restrict__ Vn, short* __restrict__ attnT) {
  __shared__ short KT[2][4096];   // [buf][64 rows][64 d]  8 KB per buf
  __shared__ short VT[2][4096];   // [buf][64 ch][64 kv]
  int blk0 = blockIdx.x;
  int blk = (blk0 & 7) * 128 + (blk0 >> 3);  // 1024 = 8 XCD x 128: batch->XCD
  int qb = blk & 15, h = (blk >> 4) & 7, b = blk >> 7;
  int t = threadIdx.x;
  int w = t >> 6, lane = t & 63, n16 = lane & 15, quad = lane >> 4;
  int q0 = qb * 64 + w * 16;
  int qhi = quad >> 1;
  int srcA = ((quad & 1) << 5) + n16;
  int srcB = srcA + 16;

  const short* Qp = Qt + (size_t)(b * 8 + h) * 1024 * 64;
  const short* Kp = Kt + (size_t)(b * 8 + h) * 1024 * 64;
  const short* Vp = Vn + (size_t)(b * 512 + h * 64) * 1024;

  short8 qa[2];
  for (int f = 0; f < 2; f++)
    qa[f] = *reinterpret_cast<const short8*>(
        Qp + (size_t)(q0 + n16) * 64 + f * 32 + quad * 8);

  floatx4 O[4];
  float l = 0.f;
  for (int i = 0; i < 4; i++) O[i] = (floatx4){0.f, 0.f, 0.f, 0.f};

  // staging chunk geometry (per thread: 2 chunks of 16 B per tile)
  int p0 = t * 16, p1 = 4096 + t * 16;           // LDS byte offsets
  int r0 = p0 >> 7, c0 = (p0 & 127) ^ ((r0 & 7) << 4);
  int r1 = p1 >> 7, c1 = (p1 & 127) ^ ((r1 & 7) << 4);

#define STAGEKV(buf, ktv)                                                    \
  do {                                                                       \
    const char* Kb_ = (const char*)Kp + (ktv) * 8192;                        \
    const char* Vb_ = (const char*)Vp + (ktv) * 128;                         \
    glds16((const short*)(Kb_ + r0 * 128 + c0), &KT[buf][p0 >> 1]);          \
    glds16((const short*)(Kb_ + r1 * 128 + c1), &KT[buf][p1 >> 1]);          \
    glds16((const short*)(Vb_ + (size_t)r0 * 2048 + c0), &VT[buf][p0 >> 1]); \
    glds16((const short*)(Vb_ + (size_t)r1 * 2048 + c1), &VT[buf][p1 >> 1]); \
  } while (0)

// swizzled LDS byte offset for a 16B read at (row, colbyte)
#define LDSOFF(row, colb) ((row) * 128 + (((colb) ^ (((row) & 7) << 4))))

  STAGEKV(0, 0);
#pragma unroll 1
  for (int kt = 0; kt < 16; kt++) {
    int cur = kt & 1;
    __syncthreads();                       // drains staging + prior ds_reads
    if (kt < 15) STAGEKV(cur ^ 1, kt + 1);

    short8 kf[4][2], v[4][2];
#pragma unroll
    for (int nt = 0; nt < 4; nt++)
#pragma unroll
      for (int f = 0; f < 2; f++) {
        kf[nt][f] = *reinterpret_cast<const short8*>(
            (const char*)&KT[cur][0] +
            LDSOFF(nt * 16 + n16, f * 64 + quad * 16));
        v[nt][f] = *reinterpret_cast<const short8*>(
            (const char*)&VT[cur][0] +
            LDSOFF(nt * 16 + n16, f * 64 + quad * 16));
      }

    floatx4 T[4];
#pragma unroll
    for (int nt = 0; nt < 4; nt++) {
      floatx4 s_ = (floatx4){0.f, 0.f, 0.f, 0.f};
      s_ = MFMA(kf[nt][0], qa[0], s_);
      T[nt] = MFMA(kf[nt][1], qa[1], s_);
    }
    unsigned u[4][2];
#pragma unroll
    for (int nt = 0; nt < 4; nt++) {
      float p0_ = __expf(T[nt][0]);
      float p1_ = __expf(T[nt][1]);
      float p2_ = __expf(T[nt][2]);
      float p3_ = __expf(T[nt][3]);
      l += (p0_ + p1_) + (p2_ + p3_);
      u[nt][0] = pk2(p0_, p1_);
      u[nt][1] = pk2(p2_, p3_);
    }
    short8 pa[2];
#pragma unroll
    for (int f = 0; f < 2; f++) {
      unsigned a0 = (unsigned)__shfl((int)u[2 * f + 0][0], srcA);
      unsigned a1 = (unsigned)__shfl((int)u[2 * f + 1][0], srcA);
      unsigned b0 = (unsigned)__shfl((int)u[2 * f + 0][1], srcA);
      unsigned b1 = (unsigned)__shfl((int)u[2 * f + 1][1], srcA);
      unsigned c0_ = (unsigned)__shfl((int)u[2 * f + 0][0], srcB);
      unsigned c1_ = (unsigned)__shfl((int)u[2 * f + 1][0], srcB);
      unsigned d0 = (unsigned)__shfl((int)u[2 * f + 0][1], srcB);
      unsigned d1 = (unsigned)__shfl((int)u[2 * f + 1][1], srcB);
      uint4 wv;
      wv.x = qhi ? a1 : a0;
      wv.y = qhi ? b1 : b0;
      wv.z = qhi ? c1_ : c0_;
      wv.w = qhi ? d1 : d0;
      pa[f] = __builtin_bit_cast(short8, wv);
    }
    __builtin_amdgcn_s_setprio(1);
#pragma unroll
    for (int nd = 0; nd < 4; nd++) {
      O[nd] = MFMA(pa[0], v[nd][0], O[nd]);
      O[nd] = MFMA(pa[1], v[nd][1], O[nd]);
    }
    __builtin_amdgcn_s_setprio(0);
  }
#undef STAGEKV
#undef LDSOFF

  // epilogue: reduce l over quads, normalize, coalesce via per-wave scratch.
  {
    float s = l;
    s += __shfl_xor(s, 16);
    s += __shfl_xor(s, 32);
    // KT[0] is free: per-wave 1024-short slice as [16 rows][64 ch]
    short* scr = &KT[0][0] + w * 1024;
#pragma unroll
    for (int nd = 0; nd < 4; nd++)
#pragma unroll
      for (int r = 0; r < 4; r++) {
        float linv = 1.0f / __shfl(s, quad * 4 + r);
        scr[(quad * 4 + r) * 64 + nd * 16 + n16] = f2bs(O[nd][r] * linv);
      }
    // same-wave readback (lgkmcnt auto-inserted), 2 x 16B coalesced stores
#pragma unroll
    for (int j = 0; j < 2; j++) {
      int c = lane * 2 + j;               // 128 chunks of 16B per wave
      int row = c >> 3, cb = (c & 7) * 16;
      short8 vvv = *reinterpret_cast<const short8*>(
          (const char*)scr + row * 128 + cb);
      *reinterpret_cast<short8*>(
          attnT + ((size_t)b * 1024 + q0 + row) * 512 + h * 64 + cb / 2) = vvv;
    }
  }
}

// ---------------------------------------------------------------------------
// Kernel 4: projection GEMM + bias + residual, 64x64 tiles + XCD swizzle
// (unchanged from r16).
// ---------------------------------------------------------------------------
__global__ __launch_bounds__(256) void gemm_out(
    const short* __restrict__ Wb, const short* __restrict__ Xt,
    const float* __restrict__ bias, const float* __restrict__ resid,
    float* __restrict__ out) {
  __shared__ short As[2][2048];   // 64 rows x 32 k
  __shared__ short Bs[2][2048];
  int blk0 = blockIdx.x;
  int blk = (blk0 & 7) * 128 + (blk0 >> 3);  // 1024 = 8 XCD x 128: batch->XCD
  int bb = blk >> 7;
  int rem = blk & 127;
  int by = rem >> 4, bx = rem & 15;
  int m0 = by * 64, n0 = bx * 64;
  int t = threadIdx.x;
  int w = t >> 6, lane = t & 63, n16 = lane & 15, quad = lane >> 4;
  int wm = (w >> 1) * 32, wn = (w & 1) * 32;

  const short* Wa = Wb + (size_t)(m0 + (t >> 2)) * 512 + (t & 3) * 8;
  const short* Xa = Xt + (size_t)bb * 1024 * 512 +
                    (size_t)(n0 + (t >> 2)) * 512 + (t & 3) * 8;

#define STAGE(buf, kk)                                                \
  do {                                                                \
    glds16(Wa + (kk), &As[buf][t * 8]);                               \
    glds16(Xa + (kk), &Bs[buf][t * 8]);                               \
  } while (0)

  floatx4 acc[2][2];
  for (int i = 0; i < 2; i++)
    for (int j = 0; j < 2; j++) acc[i][j] = (floatx4){0.f, 0.f, 0.f, 0.f};

  STAGE(0, 0);
#pragma unroll 1
  for (int ks = 0; ks < 16; ks++) {
    int cur = ks & 1;
    __syncthreads();
    if (ks < 15) STAGE(cur ^ 1, (ks + 1) * 32);
    short8 a[2], b[2];
    for (int im = 0; im < 2; im++)
      a[im] = *reinterpret_cast<const short8*>(
          &As[cur][(wm + im * 16 + n16) * 32 + quad * 8]);
    for (int in = 0; in < 2; in++)
      b[in] = *reinterpret_cast<const short8*>(
          &Bs[cur][(wn + in * 16 + n16) * 32 + quad * 8]);
    for (int im = 0; im < 2; im++)
      for (int in = 0; in < 2; in++)
        acc[im][in] = MFMA(a[im], b[in], acc[im][in]);
  }
#undef STAGE

  for (int im = 0; im < 2; im++) {
    int m = m0 + wm + im * 16 + quad * 4;
    float4 bi = *reinterpret_cast<const float4*>(&bias[m]);
    for (int in = 0; in < 2; in++) {
      int nn = n0 + wn + in * 16 + n16;
      size_t idx = ((size_t)bb * 512 + m) * 1024 + nn;
      out[idx]        = acc[im][in][0] + bi.x + resid[idx];
      out[idx + 1024] = acc[im][in][1] + bi.y + resid[idx + 1024];
      out[idx + 2048] = acc[im][in][2] + bi.z + resid[idx + 2048];
      out[idx + 3072] = acc[im][in][3] + bi.w + resid[idx + 3072];
    }
  }
}

// ---------------------------------------------------------------------------
extern "C" void kernel_launch(void* const* d_in, const int* in_sizes, int n_in,
                              void* d_out, int out_size, void* d_ws, size_t ws_size,
                              hipStream_t stream) {
  const float* x     = (const float*)d_in[0];
  const float* gamma = (const float*)d_in[1];
  const float* beta  = (const float*)d_in[2];
  const float* w_in  = (const float*)d_in[3];
  const float* b_in  = (const float*)d_in[4];
  const float* w_out = (const float*)d_in[5];
  const float* b_out = (const float*)d_in[6];
  float* out = (float*)d_out;

  char* ws = (char*)d_ws;
  short* ht    = (short*)ws;                    //  8 MiB [8][1024][512]
  short* Qt    = (short*)(ws + (8u  << 20));    //  8 MiB [64][1024][64]
  short* Kt    = (short*)(ws + (16u << 20));    //  8 MiB [64][1024][64]
  short* Vn    = (short*)(ws + (24u << 20));    //  8 MiB [8][512][1024]
  short* attnT = (short*)(ws + (32u << 20));    //  8 MiB [8][1024][512]
  short* wbf1  = (short*)(ws + (40u << 20));    //  1.5 MiB
  short* wbf2  = (short*)(ws + (42u << 20));    //  0.5 MiB

  gn_cast_fused<<<1280, 256, 0, stream>>>(x, gamma, beta, ht,
                                          w_in, wbf1, w_out, wbf2);
  gemm_qkv<<<768, 256, 0, stream>>>(wbf1, ht, b_in, Qt, Kt, Vn);
  attn_mfma<<<1024, 256, 0, stream>>>(Qt, Kt, Vn, attnT);
  gemm_out<<<1024, 256, 0, stream>>>(wbf2, attnT, b_out, x, out);
}